// Round 11
// baseline (607.714 us; speedup 1.0000x reference)
//
#include <hip/hip_runtime.h>

// Problem dims
#define NB 256    // batch
#define ND 32     // T_dec
#define NTE 128   // T_enc
#define NH 512    // hidden
#define NEMB 300  // E
#define NV 5000   // vocab

typedef unsigned short u16;
typedef __attribute__((ext_vector_type(8))) short bf16x8;
typedef __attribute__((ext_vector_type(4))) float f32x4;

__device__ __forceinline__ float sigm(float x) { return 1.f / (1.f + expf(-x)); }

__device__ __forceinline__ u16 f2bf(float x) {
  union { float f; unsigned u; } v; v.f = x;
  unsigned r = v.u + 0x7fffu + ((v.u >> 16) & 1u);
  return (u16)(r >> 16);
}
__device__ __forceinline__ float bf2f(u16 h) {
  union { unsigned u; float f; } v; v.u = ((unsigned)h) << 16; return v.f;
}

#define GLOBAL_AS __attribute__((address_space(1)))
#define LDS_AS __attribute__((address_space(3)))
__device__ __forceinline__ void g2l16(const void* g, void* l) {
  __builtin_amdgcn_global_load_lds((GLOBAL_AS void*)g, (LDS_AS void*)l, 16, 0, 0);
}

// =============== bf16 MFMA NT GEMM: D = sum_pairs A_p @ B_p^T (+bias) ===============
// Up to 3 (A,B) pairs (same lda/ldb/K) accumulate into one acc (split-bf16 path).
// fp32 out: off = (row & msk)*s1 + (row>>rbs)*s2 + n. bf16 out: hi (Dbf) + optional lo (Dbf2).
// XCD-bijective block swizzle (T1): requires gridX*gridY % 8 == 0 (all call sites comply).
struct MGP {
  const u16* A; long lda;
  const u16* B; long ldb;
  const u16* A2; const u16* B2;
  const u16* A3; const u16* B3;
  float* D; int rbs; long s1, s2;
  u16* Dbf; u16* Dbf2; long ldbf; int padN;
  const float* bias;
  int N, K;
};

__global__ __launch_bounds__(256) void mg_gemm(MGP p) {
  __shared__ __align__(16) u16 As[128 * 32];
  __shared__ __align__(16) u16 Bs[128 * 32];
  const int tid = threadIdx.x;
  const int l = tid & 63, w = tid >> 6;
  // T1: chunked XCD swizzle (bijective since nwg % 8 == 0)
  const int nwg = gridDim.x * gridDim.y;
  const int wg = blockIdx.y * gridDim.x + blockIdx.x;
  const int swz = (wg & 7) * (nwg >> 3) + (wg >> 3);
  const int m0 = (swz % gridDim.x) * 128, n0 = (swz / gridDim.x) * 128;
  const int r4 = l >> 2, c8 = (l & 3) << 3;
  const int wm = (w >> 1) * 64, wn = (w & 1) * 64;

  f32x4 acc[4][4] = {};

#pragma unroll 1
  for (int pr = 0; pr < 3; ++pr) {
    const u16 *Ap, *Bp;
    if (pr == 0) { Ap = p.A; Bp = p.B; }
    else if (pr == 1) { Ap = p.A2; Bp = p.B2; }
    else { Ap = p.A3; Bp = p.B3; }
    if (!Ap) break;
    const u16* Abase = Ap + (long)m0 * p.lda;
    const u16* Bbase = Bp + (long)n0 * p.ldb;

    for (int k0 = 0; k0 < p.K; k0 += 32) {
#pragma unroll
      for (int c = 0; c < 2; ++c) {
        const int rb0 = c * 64 + w * 16;
        g2l16(Abase + (long)(rb0 + r4) * p.lda + k0 + c8, &As[rb0 * 32]);
        g2l16(Bbase + (long)(rb0 + r4) * p.ldb + k0 + c8, &Bs[rb0 * 32]);
      }
      __syncthreads();
      bf16x8 af[4], bfv[4];
#pragma unroll
      for (int f = 0; f < 4; ++f) {
        af[f]  = *(const bf16x8*)&As[(wm + f * 16 + (l & 15)) * 32 + ((l >> 4) << 3)];
        bfv[f] = *(const bf16x8*)&Bs[(wn + f * 16 + (l & 15)) * 32 + ((l >> 4) << 3)];
      }
#pragma unroll
      for (int i = 0; i < 4; ++i)
#pragma unroll
        for (int j = 0; j < 4; ++j)
          acc[i][j] = __builtin_amdgcn_mfma_f32_16x16x32_bf16(af[i], bfv[j], acc[i][j], 0, 0, 0);
      __syncthreads();
    }
  }

  const int cc = l & 15, cr = (l >> 4) << 2;
  const long msk = ((long)1 << p.rbs) - 1;
#pragma unroll
  for (int fn = 0; fn < 4; ++fn) {
    const int n = n0 + wn + fn * 16 + cc;
    const bool nok = n < p.N;
    const float badd = (p.bias && nok) ? p.bias[n] : 0.f;
#pragma unroll
    for (int fm = 0; fm < 4; ++fm) {
#pragma unroll
      for (int j = 0; j < 4; ++j) {
        const long row = m0 + wm + fm * 16 + cr + j;
        float v = acc[fm][fn][j] + badd;
        if (p.D && nok)
          p.D[(row & msk) * p.s1 + (row >> p.rbs) * p.s2 + n] = v;
        if (p.Dbf && n < p.padN) {
          u16 hv = nok ? f2bf(v) : (u16)0;
          p.Dbf[row * p.ldbf + n] = hv;
          if (p.Dbf2)
            p.Dbf2[row * p.ldbf + n] = nok ? f2bf(v - bf2f(hv)) : (u16)0;
        }
      }
    }
  }
}

// =============== batched enc_dot (split-bf16 MFMA): ed[b] = enc[b] @ wdec[:,b,:]^T ===============
__global__ __launch_bounds__(256) void encdot_kernel(const float* __restrict__ enc,
                                                     const u16* __restrict__ wh,
                                                     const u16* __restrict__ wl,
                                                     float* __restrict__ ed) {
  const int b = blockIdx.x;
  const int tid = threadIdx.x, l = tid & 63, w = tid >> 6;
  const int m0 = w * 32;
  const int lr = l & 15, lk = l >> 4;
  const float* eb = enc + (long)b * NTE * NH;
  f32x4 acc[2][2] = {};

#pragma unroll 1
  for (int ks = 0; ks < 16; ++ks) {
    const int k0 = ks * 32 + lk * 8;
    bf16x8 ah[2], alo[2];
#pragma unroll
    for (int mi = 0; mi < 2; ++mi) {
      const float* src = eb + (long)(m0 + mi * 16 + lr) * NH + k0;
      float4 x0 = *(const float4*)(src);
      float4 x1 = *(const float4*)(src + 4);
      float xs[8] = {x0.x, x0.y, x0.z, x0.w, x1.x, x1.y, x1.z, x1.w};
      bf16x8 h, lo;
#pragma unroll
      for (int q = 0; q < 8; ++q) {
        u16 hv = f2bf(xs[q]);
        h[q] = (short)hv;
        lo[q] = (short)f2bf(xs[q] - bf2f(hv));
      }
      ah[mi] = h; alo[mi] = lo;
    }
#pragma unroll
    for (int ni = 0; ni < 2; ++ni) {
      const long brow = ((long)(ni * 16 + lr) * NB + b) * 512 + k0;
      bf16x8 bh = *(const bf16x8*)(wh + brow);
      bf16x8 bl = *(const bf16x8*)(wl + brow);
#pragma unroll
      for (int mi = 0; mi < 2; ++mi) {
        acc[mi][ni] = __builtin_amdgcn_mfma_f32_16x16x32_bf16(ah[mi], bh, acc[mi][ni], 0, 0, 0);
        acc[mi][ni] = __builtin_amdgcn_mfma_f32_16x16x32_bf16(ah[mi], bl, acc[mi][ni], 0, 0, 0);
        acc[mi][ni] = __builtin_amdgcn_mfma_f32_16x16x32_bf16(alo[mi], bh, acc[mi][ni], 0, 0, 0);
      }
    }
  }

  const int cr = lk << 2;
  float* edb = ed + (long)b * NTE * ND;
#pragma unroll
  for (int mi = 0; mi < 2; ++mi)
#pragma unroll
    for (int ni = 0; ni < 2; ++ni)
#pragma unroll
      for (int j = 0; j < 4; ++j)
        edb[(long)(m0 + mi * 16 + cr + j) * ND + ni * 16 + lr] = acc[mi][ni][j];
}

// =============== per-step LSTM: grid (4 bg, 32 jg), block 256 = 4 waves ===============
// Kernel boundary = device-wide barrier (cheapest on 8 non-coherent XCDs; R8 lesson).
// G is bf16 gate-interleaved: 8B (4 gates) per (b,j).
__global__ __launch_bounds__(256) void step_lstm2(const u16* __restrict__ hprev, long ldh,
                                                  const u16* __restrict__ whh,
                                                  const u16* __restrict__ Gt,
                                                  float* __restrict__ c,
                                                  u16* __restrict__ hout) {
  __shared__ __align__(16) u16 WhhS[64 * 512];  // 64KB
  const int tid = threadIdx.x, l = tid & 63, w = tid >> 6;
  const int mb = blockIdx.x * 64, j0 = blockIdx.y * 16;

#pragma unroll
  for (int it = 0; it < 16; ++it) {
    const int row = it * 4 + w;
    const int g = row >> 4, r = row & 15;
    const long goff = ((long)(g * 512 + j0 + r)) * 512 + ((l ^ (row & 7)) << 3);
    g2l16(whh + goff, &WhhS[row * 512]);
  }

  bf16x8 av[16];
  const u16* hb = hprev + (long)(mb + w * 16 + (l & 15)) * ldh + ((l >> 4) << 3);
#pragma unroll
  for (int ks = 0; ks < 16; ++ks) av[ks] = *(const bf16x8*)(hb + ks * 32);

  __syncthreads();

  f32x4 acc[4] = {};
#pragma unroll
  for (int ks = 0; ks < 16; ++ks) {
#pragma unroll
    for (int g = 0; g < 4; ++g) {
      const int row = g * 16 + (l & 15);
      const int cl = (ks * 4 + (l >> 4)) ^ (l & 7);
      bf16x8 bv = *(const bf16x8*)((const char*)WhhS + row * 1024 + (cl << 4));
      acc[g] = __builtin_amdgcn_mfma_f32_16x16x32_bf16(av[ks], bv, acc[g], 0, 0, 0);
    }
  }

  const int j = j0 + (l & 15);
  const int bb = mb + w * 16 + ((l >> 4) << 2);
#pragma unroll
  for (int jr = 0; jr < 4; ++jr) {
    const int b = bb + jr;
    ushort4 gv = *(const ushort4*)(Gt + (long)b * 2048 + j * 4);  // {i,f,g,o} bf16
    float ig = sigm(acc[0][jr] + bf2f(gv.x));
    float fg = sigm(acc[1][jr] + bf2f(gv.y));
    float gg = tanhf(acc[2][jr] + bf2f(gv.z));
    float og = sigm(acc[3][jr] + bf2f(gv.w));
    const long ci = (long)b * NH + j;
    float cn = fg * c[ci] + ig * gg;
    c[ci] = cn;
    hout[(long)b * 1024 + j] = f2bf(og * tanhf(cn));
  }
}

// =============== v_norm rows -> bf16 [5120][320] (zero-padded) ===============
__global__ void vnorm_kernel(const float* __restrict__ v, u16* __restrict__ vn) {
  int r = blockIdx.x, tid = threadIdx.x;
  if (r >= NV) {
    for (int e = tid; e < 320; e += 64) vn[(long)r * 320 + e] = 0;
    return;
  }
  float ss = 0.f;
  for (int e = tid; e < NEMB; e += 64) { float x = v[(long)r * NEMB + e]; ss += x * x; }
#pragma unroll
  for (int o = 32; o > 0; o >>= 1) ss += __shfl_down(ss, o, 64);
  ss = __shfl(ss, 0, 64);
  float sc = 1.f / fmaxf(sqrtf(ss), 1e-12f);
  for (int e = tid; e < 320; e += 64)
    vn[(long)r * 320 + e] = (e < NEMB) ? f2bf(v[(long)r * NEMB + e] * sc) : (u16)0;
}

// =============== fused prep ===============
#define SEG_A 2621440L   // in_bf [8192][320]
#define SEG_B 81920L     // ws1_bf [256][320]
#define SEG_C 1703936L   // wih_bf [2048][832] gate-interleaved rows
#define SEG_D 1048576L   // whh_bf [2048][512]
#define SEG_E 393216L    // wv_bf [384][1024]
#define SEG_F 163840L    // wae hi/lo [512][320]
#define SEG_G 2048L      // bsumv gate-interleaved
#define SEG_H 131072L    // h0_bf
#define SEG_I 131072L    // c_buf = c0 copy
#define PREP_TOT (SEG_A + SEG_B + SEG_C + SEG_D + SEG_E + SEG_F + SEG_G + SEG_H + SEG_I)

__global__ void prep_all(const float* __restrict__ input, const float* __restrict__ Ws1,
                         const float* __restrict__ Wih, const float* __restrict__ Whh,
                         const float* __restrict__ Wv, const float* __restrict__ Watt,
                         const float* __restrict__ bih, const float* __restrict__ bhh,
                         const float* __restrict__ h0, const float* __restrict__ c0,
                         u16* __restrict__ in_bf, u16* __restrict__ ws1_bf,
                         u16* __restrict__ wih_bf, u16* __restrict__ whh_bf,
                         u16* __restrict__ wv_bf, u16* __restrict__ wae_hi,
                         u16* __restrict__ wae_lo,
                         float* __restrict__ bsumv, u16* __restrict__ h0_bf,
                         float* __restrict__ c_buf) {
  long idx = (long)blockIdx.x * 256 + threadIdx.x;
  if (idx < SEG_A) {
    int row = (int)(idx / 320), e = (int)(idx % 320);
    in_bf[idx] = (e < NEMB) ? f2bf(input[(long)row * NEMB + e]) : (u16)0;
    return;
  }
  idx -= SEG_A;
  if (idx < SEG_B) {
    int r = (int)(idx / 320), e = (int)(idx % 320);
    ws1_bf[idx] = (r < 150 && e < NEMB) ? f2bf(Ws1[r * NEMB + e]) : (u16)0;
    return;
  }
  idx -= SEG_B;
  if (idx < SEG_C) {
    int rp = (int)(idx / 832), cpos = (int)(idx % 832);
    int g = rp & 3, j = rp >> 2;
    wih_bf[idx] = (cpos < 812) ? f2bf(Wih[(long)(g * 512 + j) * 812 + cpos]) : (u16)0;
    return;
  }
  idx -= SEG_C;
  if (idx < SEG_D) { whh_bf[idx] = f2bf(Whh[idx]); return; }
  idx -= SEG_D;
  if (idx < SEG_E) {
    int r = (int)(idx >> 10);
    wv_bf[idx] = (r < NEMB) ? f2bf(Wv[idx]) : (u16)0;
    return;
  }
  idx -= SEG_E;
  if (idx < SEG_F) {  // wae hi/lo split
    int k = (int)(idx / 320), e = (int)(idx % 320);
    float x = (e < NEMB) ? Watt[(long)e * 1024 + 512 + k] : 0.f;
    u16 hv = f2bf(x);
    wae_hi[idx] = hv;
    wae_lo[idx] = f2bf(x - bf2f(hv));
    return;
  }
  idx -= SEG_F;
  if (idx < SEG_G) {
    int g = (int)(idx & 3), j = (int)(idx >> 2);
    bsumv[idx] = bih[g * 512 + j] + bhh[g * 512 + j];
    return;
  }
  idx -= SEG_G;
  if (idx < SEG_H) { h0_bf[idx] = f2bf(h0[idx]); return; }
  idx -= SEG_H;
  if (idx < SEG_I) c_buf[idx] = c0[idx];
}

// s_self[row] = Ws2b + sum_i tanh(hid[row][i]) * Ws2[i]
__global__ __launch_bounds__(256) void sself_reduce(const float* __restrict__ hid,
                                                    const float* __restrict__ Ws2,
                                                    const float* __restrict__ Ws2b,
                                                    float* __restrict__ s_self) {
  int row = blockIdx.x * 4 + (threadIdx.x >> 6);
  int lane = threadIdx.x & 63;
  float acc = 0.f;
  for (int i = lane; i < 150; i += 64) acc += tanhf(hid[(long)row * 160 + i]) * Ws2[i];
#pragma unroll
  for (int o = 32; o > 0; o >>= 1) acc += __shfl_down(acc, o, 64);
  if (lane == 0) s_self[row] = acc + Ws2b[0];
}

// =============== dec_inp: prefix-scan softmax -> dec hi/lo (split) + xcat ===============
__global__ __launch_bounds__(256) void decinp2_kernel(const float* __restrict__ input,
                                                      const float* __restrict__ s_self,
                                                      u16* __restrict__ dec_hi,
                                                      u16* __restrict__ dec_lo,
                                                      u16* __restrict__ xcat) {
  __shared__ float x[ND * NEMB];  // 38.4 KB
  __shared__ float ew[ND], invD[ND];
  const int b = blockIdx.x, tid = threadIdx.x;
  const float4* src = (const float4*)(input + (long)b * ND * NEMB);
  for (int i = tid; i < ND * NEMB / 4; i += 256) ((float4*)x)[i] = src[i];
  if (tid == 0) {
    float M = -1e30f;
    for (int u = 0; u < ND; u++) M = fmaxf(M, s_self[b * ND + u]);
    float s = 0.f;
    for (int u = 0; u < ND; u++) {
      float e = expf(s_self[b * ND + u] - M);
      ew[u] = e; s += e; invD[u] = 1.f / s;
    }
  }
  __syncthreads();
  for (int e = tid; e < NEMB; e += 256) {
    float acc = 0.f;
    for (int u = 0; u < ND; u++) {
      acc = fmaf(ew[u], x[u * NEMB + e], acc);
      float d = acc * invD[u];
      const long row = (long)u * NB + b;
      u16 hv = f2bf(d);
      dec_hi[row * 320 + e] = hv;
      dec_lo[row * 320 + e] = f2bf(d - bf2f(hv));
      xcat[row * 832 + e] = hv;
    }
  }
  for (int idx = tid; idx < ND * 20; idx += 256) {
    int u = idx / 20, e = 300 + idx % 20;
    const long row = (long)u * NB + b;
    dec_hi[row * 320 + e] = 0;
    dec_lo[row * 320 + e] = 0;
    xcat[row * 832 + 512 + e] = 0;  // K-pad cols 812..831
  }
}

// =============== enc-softmax + x_att -> bf16 into xcat[300..811] & hcat[512..1023] ===============
__global__ __launch_bounds__(256) void xatt_kernel(const float* __restrict__ enc_dot,
                                                   const float* __restrict__ enc,
                                                   u16* __restrict__ xcat,
                                                   u16* __restrict__ hcat) {
  __shared__ float al[NTE][ND + 1];
  int b = blockIdx.x, tid = threadIdx.x;
  for (int i = tid; i < NTE * ND; i += 256) al[i >> 5][i & 31] = enc_dot[(long)b * NTE * ND + i];
  __syncthreads();
  if (tid < ND) {
    int t = tid;
    float m = -1e30f;
    for (int tp = 0; tp < NTE; tp++) m = fmaxf(m, al[tp][t]);
    float s = 0.f;
    for (int tp = 0; tp < NTE; tp++) { float e = expf(al[tp][t] - m); al[tp][t] = e; s += e; }
    float inv = 1.f / s;
    for (int tp = 0; tp < NTE; tp++) al[tp][t] *= inv;
  }
  __syncthreads();
  int tx = tid & 31, ty = tid >> 5;
  const float* eb = enc + (long)b * NTE * NH;
  for (int hc = 0; hc < NH; hc += 128) {
    float acc[4][4] = {};
    for (int tp = 0; tp < NTE; tp++) {
      float4 ev = *(const float4*)(eb + (long)tp * NH + hc + (tx << 2));
#pragma unroll
      for (int i = 0; i < 4; i++) {
        float a = al[tp][(ty << 2) + i];
        acc[i][0] = fmaf(a, ev.x, acc[i][0]);
        acc[i][1] = fmaf(a, ev.y, acc[i][1]);
        acc[i][2] = fmaf(a, ev.z, acc[i][2]);
        acc[i][3] = fmaf(a, ev.w, acc[i][3]);
      }
    }
#pragma unroll
    for (int i = 0; i < 4; i++) {
      const long row = (long)((ty << 2) + i) * NB + b;
      const int h = hc + (tx << 2);
      ushort4 u;
      u.x = f2bf(acc[i][0]); u.y = f2bf(acc[i][1]);
      u.z = f2bf(acc[i][2]); u.w = f2bf(acc[i][3]);
      *(ushort4*)(xcat + row * 832 + 300 + h) = u;
      *(ushort4*)(hcat + row * 1024 + 512 + h) = u;
    }
  }
}

// =============== host ===============
extern "C" void kernel_launch(void* const* d_in, const int* in_sizes, int n_in,
                              void* d_out, int out_size, void* d_ws, size_t ws_size,
                              hipStream_t stream) {
  const float* input = (const float*)d_in[0];
  const float* enc   = (const float*)d_in[1];
  const float* h0   = (const float*)d_in[3];
  const float* c0   = (const float*)d_in[4];
  const float* Watt = (const float*)d_in[5];
  const float* Wv   = (const float*)d_in[7];
  const float* Wvb  = (const float*)d_in[8];
  const float* Ws1  = (const float*)d_in[9];
  const float* Ws1b = (const float*)d_in[10];
  const float* Ws2  = (const float*)d_in[11];
  const float* Ws2b = (const float*)d_in[12];
  const float* vmat = (const float*)d_in[13];
  const float* Wih  = (const float*)d_in[14];
  const float* Whh  = (const float*)d_in[15];
  const float* bih  = (const float*)d_in[16];
  const float* bhh  = (const float*)d_in[17];
  float* out = (float*)d_out;

  // workspace (float units, 16-float aligned)
  float* base = (float*)d_ws;
  size_t off = 0;
  auto alloc = [&](size_t n) { float* p = base + off; off += (n + 15) & ~15ull; return p; };
  u16* vnorm_bf = (u16*)alloc((size_t)5120 * 320 / 2);
  u16* wae_hi   = (u16*)alloc((size_t)512 * 320 / 2);
  u16* wae_lo   = (u16*)alloc((size_t)512 * 320 / 2);
  u16* wih_bf   = (u16*)alloc((size_t)2048 * 832 / 2);
  u16* whh_bf   = (u16*)alloc((size_t)2048 * 512 / 2);
  u16* wv_bf    = (u16*)alloc((size_t)384 * 1024 / 2);
  u16* ws1_bf   = (u16*)alloc((size_t)256 * 320 / 2);
  float* bsumv  = alloc(4 * NH);
  float* s_self = alloc(NB * ND);
  u16* dec_hi   = (u16*)alloc((size_t)ND * NB * 320 / 2);
  u16* dec_lo   = (u16*)alloc((size_t)ND * NB * 320 / 2);
  u16* xcat     = (u16*)alloc((size_t)ND * NB * 832 / 2);
  u16* hcat     = (u16*)alloc((size_t)ND * NB * 1024 / 2);
  u16* hi2_bf   = (u16*)alloc((size_t)ND * NB * 320 / 2);
  u16* h0_bf    = (u16*)alloc((size_t)NB * NH / 2);
  float* c_buf  = alloc((size_t)NB * NH);
  float* region = alloc((size_t)ND * NB * 4 * NH);  // 16.78M floats, overlaid:
  u16* wdec_hi  = (u16*)region;                      // [8192][512] u16 (floats 0..2.10M)
  u16* wdec_lo  = (u16*)(region + 2097152);          // [8192][512] u16 (2.10M..4.19M)
  float* enc_dot = region + 4194304;                 // [b][128][32] f32 (4.19M..5.24M)
  u16*   in_bf   = (u16*)(region + 6000000);         // [8192][320] bf16, dead after hid gemm
  float* hid     = region + 7500000;                 // [8192][160] f32, dead after sself_reduce
  u16*   inp_g   = (u16*)region;                     // [8192][2048] bf16, written after all die

  auto mg = [&](MGP p, int gm, int gn) { mg_gemm<<<dim3(gm, gn), 256, 0, stream>>>(p); };

  prep_all<<<(int)((PREP_TOT + 255) / 256), 256, 0, stream>>>(
      input, Ws1, Wih, Whh, Wv, Watt, bih, bhh, h0, c0,
      in_bf, ws1_bf, wih_bf, whh_bf, wv_bf, wae_hi, wae_lo, bsumv, h0_bf, c_buf);
  vnorm_kernel<<<5120, 64, 0, stream>>>(vmat, vnorm_bf);

  {  // hid = input-tanh GEMM: [8192][320] @ [256][320]^T -> fp32 [8192][160-strided], +Ws1b
    MGP p{};
    p.A = in_bf; p.lda = 320; p.B = ws1_bf; p.ldb = 320;
    p.D = hid; p.rbs = 30; p.s1 = 160; p.s2 = 0;
    p.bias = Ws1b; p.N = 150; p.K = 320;
    mg(p, 64, 2);
  }
  sself_reduce<<<2048, 256, 0, stream>>>(hid, Ws2, Ws2b, s_self);
  decinp2_kernel<<<NB, 256, 0, stream>>>(input, s_self, dec_hi, dec_lo, xcat);

  {  // wdec (split-bf16, 3 pairs, one dispatch): emits wdec hi/lo [8192][512]
    MGP p{};
    p.A = dec_hi; p.lda = 320; p.B = wae_hi; p.ldb = 320;
    p.A2 = dec_hi; p.B2 = wae_lo;
    p.A3 = dec_lo; p.B3 = wae_hi;
    p.rbs = 30;
    p.Dbf = wdec_hi; p.Dbf2 = wdec_lo; p.ldbf = 512; p.padN = 512;
    p.N = 512; p.K = 320;
    mg(p, 64, 4);
  }
  // enc_dot[b] = enc[b] @ wdec[:,b,:]^T (split-bf16 MFMA, in-register enc conversion)
  encdot_kernel<<<NB, 256, 0, stream>>>(enc, wdec_hi, wdec_lo, enc_dot);
  xatt_kernel<<<NB, 256, 0, stream>>>(enc_dot, enc, xcat, hcat);

  {  // inp_gates (gate-interleaved cols, bf16 out) = xcat @ WihP^T + biasP   [8192][2048]
    MGP p{};
    p.A = xcat; p.lda = 832; p.B = wih_bf; p.ldb = 832;
    p.rbs = 30;
    p.Dbf = inp_g; p.ldbf = 2048; p.padN = 2048;
    p.bias = bsumv; p.N = 2048; p.K = 832;
    mg(p, 64, 16);
  }

  // recurrence: one launch per step, 128 blocks (batch x j partition, no cross-block deps)
  for (int t = 0; t < ND; t++) {
    const u16* hp = (t == 0) ? h0_bf : (hcat + (size_t)(t - 1) * NB * 1024);
    long ldh = (t == 0) ? NH : 1024;
    step_lstm2<<<dim3(4, 32), 256, 0, stream>>>(hp, ldh, whh_bf,
                                                inp_g + (size_t)t * NB * 2048, c_buf,
                                                hcat + (size_t)t * NB * 1024);
  }

  {  // hi2 = [h|x_att] @ Wv^T + Wvb -> bf16 [8192][320]
    MGP p{};
    p.A = hcat; p.lda = 1024; p.B = wv_bf; p.ldb = 1024;
    p.rbs = 30;
    p.Dbf = hi2_bf; p.ldbf = 320; p.padN = 320;
    p.bias = Wvb; p.N = 300; p.K = 1024;
    mg(p, 64, 3);
  }
  {  // logits: out[b][t][v] = hi2 . v_norm  (row = t*256+b -> b*s1 + t*s2)
    MGP p{};
    p.A = hi2_bf; p.lda = 320; p.B = vnorm_bf; p.ldb = 320;
    p.D = out; p.rbs = 8; p.s1 = (long)ND * NV; p.s2 = NV;
    p.N = NV; p.K = 320;
    mg(p, 64, 40);
  }
}

// Round 12
// 595.918 us; speedup vs baseline: 1.0198x; 1.0198x over previous
//
#include <hip/hip_runtime.h>

// Problem dims
#define NB 256    // batch
#define ND 32     // T_dec
#define NTE 128   // T_enc
#define NH 512    // hidden
#define NEMB 300  // E
#define NV 5000   // vocab

typedef unsigned short u16;
typedef __attribute__((ext_vector_type(8))) short bf16x8;
typedef __attribute__((ext_vector_type(4))) float f32x4;

__device__ __forceinline__ float sigm(float x) { return 1.f / (1.f + expf(-x)); }

__device__ __forceinline__ u16 f2bf(float x) {
  union { float f; unsigned u; } v; v.f = x;
  unsigned r = v.u + 0x7fffu + ((v.u >> 16) & 1u);
  return (u16)(r >> 16);
}
__device__ __forceinline__ float bf2f(u16 h) {
  union { unsigned u; float f; } v; v.u = ((unsigned)h) << 16; return v.f;
}

#define GLOBAL_AS __attribute__((address_space(1)))
#define LDS_AS __attribute__((address_space(3)))
__device__ __forceinline__ void g2l16(const void* g, void* l) {
  __builtin_amdgcn_global_load_lds((GLOBAL_AS void*)g, (LDS_AS void*)l, 16, 0, 0);
}

// =============== bf16 MFMA NT GEMM: D = sum_pairs A_p @ B_p^T (+bias) ===============
// Up to 3 (A,B) pairs (same lda/ldb/K) accumulate into one acc (split-bf16 path).
// Double-buffered LDS prefetch pipeline (T3 minimum 2-phase): stage tile t+1 before
// computing tile t; counted vmcnt(4) + raw s_barrier (no full __syncthreads drain).
// fp32 out: off = (row & msk)*s1 + (row>>rbs)*s2 + n. bf16 out: hi (Dbf) + optional lo (Dbf2).
struct MGP {
  const u16* A; long lda;
  const u16* B; long ldb;
  const u16* A2; const u16* B2;
  const u16* A3; const u16* B3;
  float* D; int rbs; long s1, s2;
  u16* Dbf; u16* Dbf2; long ldbf; int padN;
  const float* bias;
  int N, K;
};

__global__ __launch_bounds__(256) void mg_gemm(MGP p) {
  __shared__ __align__(16) u16 As[2][128 * 32];
  __shared__ __align__(16) u16 Bs[2][128 * 32];
  const int tid = threadIdx.x;
  const int l = tid & 63, w = tid >> 6;
  const int m0 = blockIdx.x * 128, n0 = blockIdx.y * 128;
  const int r4 = l >> 2, c8 = (l & 3) << 3;
  const int wm = (w >> 1) * 64, wn = (w & 1) * 64;

  const u16* Aps[3] = {p.A, p.A2, p.A3};
  const u16* Bps[3] = {p.B, p.B2, p.B3};
  const int npair = p.A3 ? 3 : (p.A2 ? 2 : 1);
  const int kt = p.K >> 5;
  const int T = npair * kt;

  int prn = 0, k0n = 0;  // next tile to stage
  auto stage = [&](int buf) {
    const u16* Abase = Aps[prn] + (long)m0 * p.lda + k0n;
    const u16* Bbase = Bps[prn] + (long)n0 * p.ldb + k0n;
#pragma unroll
    for (int c = 0; c < 2; ++c) {
      const int rb0 = c * 64 + w * 16;
      g2l16(Abase + (long)(rb0 + r4) * p.lda + c8, &As[buf][rb0 * 32]);
      g2l16(Bbase + (long)(rb0 + r4) * p.ldb + c8, &Bs[buf][rb0 * 32]);
    }
    k0n += 32;
    if (k0n >= p.K) { k0n = 0; ++prn; }
  };

  f32x4 acc[4][4] = {};
  stage(0);  // prologue: tile 0 in flight (4 g2l16/thread)

#pragma unroll 1
  for (int t = 0; t < T; ++t) {
    const int cur = t & 1;
    if (t + 1 < T) {
      stage(cur ^ 1);  // issue next tile (4 more ops in flight)
      asm volatile("s_waitcnt vmcnt(4)" ::: "memory");  // tile t's loads landed
    } else {
      asm volatile("s_waitcnt vmcnt(0)" ::: "memory");
    }
    __builtin_amdgcn_s_barrier();        // all threads' tile-t loads landed
    __builtin_amdgcn_sched_barrier(0);   // rule #18: no ds_read hoisting above barrier
    bf16x8 af[4], bfv[4];
#pragma unroll
    for (int f = 0; f < 4; ++f) {
      af[f]  = *(const bf16x8*)&As[cur][(wm + f * 16 + (l & 15)) * 32 + ((l >> 4) << 3)];
      bfv[f] = *(const bf16x8*)&Bs[cur][(wn + f * 16 + (l & 15)) * 32 + ((l >> 4) << 3)];
    }
#pragma unroll
    for (int i = 0; i < 4; ++i)
#pragma unroll
      for (int j = 0; j < 4; ++j)
        acc[i][j] = __builtin_amdgcn_mfma_f32_16x16x32_bf16(af[i], bfv[j], acc[i][j], 0, 0, 0);
    __builtin_amdgcn_s_barrier();        // reads done (reg-delivered) before buf reuse
  }

  const int cc = l & 15, cr = (l >> 4) << 2;
  const long msk = ((long)1 << p.rbs) - 1;
#pragma unroll
  for (int fn = 0; fn < 4; ++fn) {
    const int n = n0 + wn + fn * 16 + cc;
    const bool nok = n < p.N;
    const float badd = (p.bias && nok) ? p.bias[n] : 0.f;
#pragma unroll
    for (int fm = 0; fm < 4; ++fm) {
#pragma unroll
      for (int j = 0; j < 4; ++j) {
        const long row = m0 + wm + fm * 16 + cr + j;
        float v = acc[fm][fn][j] + badd;
        if (p.D && nok)
          p.D[(row & msk) * p.s1 + (row >> p.rbs) * p.s2 + n] = v;
        if (p.Dbf && n < p.padN) {
          u16 hv = nok ? f2bf(v) : (u16)0;
          p.Dbf[row * p.ldbf + n] = hv;
          if (p.Dbf2)
            p.Dbf2[row * p.ldbf + n] = nok ? f2bf(v - bf2f(hv)) : (u16)0;
        }
      }
    }
  }
}

// =============== batched enc_dot (split-bf16 MFMA): ed[b] = enc[b] @ wdec[:,b,:]^T ===============
__global__ __launch_bounds__(256) void encdot_kernel(const float* __restrict__ enc,
                                                     const u16* __restrict__ wh,
                                                     const u16* __restrict__ wl,
                                                     float* __restrict__ ed) {
  const int b = blockIdx.x;
  const int tid = threadIdx.x, l = tid & 63, w = tid >> 6;
  const int m0 = w * 32;
  const int lr = l & 15, lk = l >> 4;
  const float* eb = enc + (long)b * NTE * NH;
  f32x4 acc[2][2] = {};

#pragma unroll 1
  for (int ks = 0; ks < 16; ++ks) {
    const int k0 = ks * 32 + lk * 8;
    bf16x8 ah[2], alo[2];
#pragma unroll
    for (int mi = 0; mi < 2; ++mi) {
      const float* src = eb + (long)(m0 + mi * 16 + lr) * NH + k0;
      float4 x0 = *(const float4*)(src);
      float4 x1 = *(const float4*)(src + 4);
      float xs[8] = {x0.x, x0.y, x0.z, x0.w, x1.x, x1.y, x1.z, x1.w};
      bf16x8 h, lo;
#pragma unroll
      for (int q = 0; q < 8; ++q) {
        u16 hv = f2bf(xs[q]);
        h[q] = (short)hv;
        lo[q] = (short)f2bf(xs[q] - bf2f(hv));
      }
      ah[mi] = h; alo[mi] = lo;
    }
#pragma unroll
    for (int ni = 0; ni < 2; ++ni) {
      const long brow = ((long)(ni * 16 + lr) * NB + b) * 512 + k0;
      bf16x8 bh = *(const bf16x8*)(wh + brow);
      bf16x8 bl = *(const bf16x8*)(wl + brow);
#pragma unroll
      for (int mi = 0; mi < 2; ++mi) {
        acc[mi][ni] = __builtin_amdgcn_mfma_f32_16x16x32_bf16(ah[mi], bh, acc[mi][ni], 0, 0, 0);
        acc[mi][ni] = __builtin_amdgcn_mfma_f32_16x16x32_bf16(ah[mi], bl, acc[mi][ni], 0, 0, 0);
        acc[mi][ni] = __builtin_amdgcn_mfma_f32_16x16x32_bf16(alo[mi], bh, acc[mi][ni], 0, 0, 0);
      }
    }
  }

  const int cr = lk << 2;
  float* edb = ed + (long)b * NTE * ND;
#pragma unroll
  for (int mi = 0; mi < 2; ++mi)
#pragma unroll
    for (int ni = 0; ni < 2; ++ni)
#pragma unroll
      for (int j = 0; j < 4; ++j)
        edb[(long)(m0 + mi * 16 + cr + j) * ND + ni * 16 + lr] = acc[mi][ni][j];
}

// =============== per-step LSTM: grid (4 bg, 32 jg), block 256 = 4 waves ===============
// Kernel boundary = device-wide barrier (cheapest on 8 non-coherent XCDs; R8 lesson).
// G is bf16 gate-interleaved: 8B (4 gates) per (b,j).
__global__ __launch_bounds__(256) void step_lstm2(const u16* __restrict__ hprev, long ldh,
                                                  const u16* __restrict__ whh,
                                                  const u16* __restrict__ Gt,
                                                  float* __restrict__ c,
                                                  u16* __restrict__ hout) {
  __shared__ __align__(16) u16 WhhS[64 * 512];  // 64KB
  const int tid = threadIdx.x, l = tid & 63, w = tid >> 6;
  const int mb = blockIdx.x * 64, j0 = blockIdx.y * 16;

#pragma unroll
  for (int it = 0; it < 16; ++it) {
    const int row = it * 4 + w;
    const int g = row >> 4, r = row & 15;
    const long goff = ((long)(g * 512 + j0 + r)) * 512 + ((l ^ (row & 7)) << 3);
    g2l16(whh + goff, &WhhS[row * 512]);
  }

  bf16x8 av[16];
  const u16* hb = hprev + (long)(mb + w * 16 + (l & 15)) * ldh + ((l >> 4) << 3);
#pragma unroll
  for (int ks = 0; ks < 16; ++ks) av[ks] = *(const bf16x8*)(hb + ks * 32);

  __syncthreads();

  f32x4 acc[4] = {};
#pragma unroll
  for (int ks = 0; ks < 16; ++ks) {
#pragma unroll
    for (int g = 0; g < 4; ++g) {
      const int row = g * 16 + (l & 15);
      const int cl = (ks * 4 + (l >> 4)) ^ (l & 7);
      bf16x8 bv = *(const bf16x8*)((const char*)WhhS + row * 1024 + (cl << 4));
      acc[g] = __builtin_amdgcn_mfma_f32_16x16x32_bf16(av[ks], bv, acc[g], 0, 0, 0);
    }
  }

  const int j = j0 + (l & 15);
  const int bb = mb + w * 16 + ((l >> 4) << 2);
#pragma unroll
  for (int jr = 0; jr < 4; ++jr) {
    const int b = bb + jr;
    ushort4 gv = *(const ushort4*)(Gt + (long)b * 2048 + j * 4);  // {i,f,g,o} bf16
    float ig = sigm(acc[0][jr] + bf2f(gv.x));
    float fg = sigm(acc[1][jr] + bf2f(gv.y));
    float gg = tanhf(acc[2][jr] + bf2f(gv.z));
    float og = sigm(acc[3][jr] + bf2f(gv.w));
    const long ci = (long)b * NH + j;
    float cn = fg * c[ci] + ig * gg;
    c[ci] = cn;
    hout[(long)b * 1024 + j] = f2bf(og * tanhf(cn));
  }
}

// =============== v_norm rows -> bf16 [5120][320] (zero-padded) ===============
__global__ void vnorm_kernel(const float* __restrict__ v, u16* __restrict__ vn) {
  int r = blockIdx.x, tid = threadIdx.x;
  if (r >= NV) {
    for (int e = tid; e < 320; e += 64) vn[(long)r * 320 + e] = 0;
    return;
  }
  float ss = 0.f;
  for (int e = tid; e < NEMB; e += 64) { float x = v[(long)r * NEMB + e]; ss += x * x; }
#pragma unroll
  for (int o = 32; o > 0; o >>= 1) ss += __shfl_down(ss, o, 64);
  ss = __shfl(ss, 0, 64);
  float sc = 1.f / fmaxf(sqrtf(ss), 1e-12f);
  for (int e = tid; e < 320; e += 64)
    vn[(long)r * 320 + e] = (e < NEMB) ? f2bf(v[(long)r * NEMB + e] * sc) : (u16)0;
}

// =============== fused prep ===============
#define SEG_A 2621440L   // in_bf [8192][320]
#define SEG_B 81920L     // ws1_bf [256][320]
#define SEG_C 1703936L   // wih_bf [2048][832] gate-interleaved rows
#define SEG_D 1048576L   // whh_bf [2048][512]
#define SEG_E 393216L    // wv_bf [384][1024]
#define SEG_F 163840L    // wae hi/lo [512][320]
#define SEG_G 2048L      // bsumv gate-interleaved
#define SEG_H 131072L    // h0_bf
#define SEG_I 131072L    // c_buf = c0 copy
#define PREP_TOT (SEG_A + SEG_B + SEG_C + SEG_D + SEG_E + SEG_F + SEG_G + SEG_H + SEG_I)

__global__ void prep_all(const float* __restrict__ input, const float* __restrict__ Ws1,
                         const float* __restrict__ Wih, const float* __restrict__ Whh,
                         const float* __restrict__ Wv, const float* __restrict__ Watt,
                         const float* __restrict__ bih, const float* __restrict__ bhh,
                         const float* __restrict__ h0, const float* __restrict__ c0,
                         u16* __restrict__ in_bf, u16* __restrict__ ws1_bf,
                         u16* __restrict__ wih_bf, u16* __restrict__ whh_bf,
                         u16* __restrict__ wv_bf, u16* __restrict__ wae_hi,
                         u16* __restrict__ wae_lo,
                         float* __restrict__ bsumv, u16* __restrict__ h0_bf,
                         float* __restrict__ c_buf) {
  long idx = (long)blockIdx.x * 256 + threadIdx.x;
  if (idx < SEG_A) {
    int row = (int)(idx / 320), e = (int)(idx % 320);
    in_bf[idx] = (e < NEMB) ? f2bf(input[(long)row * NEMB + e]) : (u16)0;
    return;
  }
  idx -= SEG_A;
  if (idx < SEG_B) {
    int r = (int)(idx / 320), e = (int)(idx % 320);
    ws1_bf[idx] = (r < 150 && e < NEMB) ? f2bf(Ws1[r * NEMB + e]) : (u16)0;
    return;
  }
  idx -= SEG_B;
  if (idx < SEG_C) {
    int rp = (int)(idx / 832), cpos = (int)(idx % 832);
    int g = rp & 3, j = rp >> 2;
    wih_bf[idx] = (cpos < 812) ? f2bf(Wih[(long)(g * 512 + j) * 812 + cpos]) : (u16)0;
    return;
  }
  idx -= SEG_C;
  if (idx < SEG_D) { whh_bf[idx] = f2bf(Whh[idx]); return; }
  idx -= SEG_D;
  if (idx < SEG_E) {
    int r = (int)(idx >> 10);
    wv_bf[idx] = (r < NEMB) ? f2bf(Wv[idx]) : (u16)0;
    return;
  }
  idx -= SEG_E;
  if (idx < SEG_F) {  // wae hi/lo split
    int k = (int)(idx / 320), e = (int)(idx % 320);
    float x = (e < NEMB) ? Watt[(long)e * 1024 + 512 + k] : 0.f;
    u16 hv = f2bf(x);
    wae_hi[idx] = hv;
    wae_lo[idx] = f2bf(x - bf2f(hv));
    return;
  }
  idx -= SEG_F;
  if (idx < SEG_G) {
    int g = (int)(idx & 3), j = (int)(idx >> 2);
    bsumv[idx] = bih[g * 512 + j] + bhh[g * 512 + j];
    return;
  }
  idx -= SEG_G;
  if (idx < SEG_H) { h0_bf[idx] = f2bf(h0[idx]); return; }
  idx -= SEG_H;
  if (idx < SEG_I) c_buf[idx] = c0[idx];
}

// s_self[row] = Ws2b + sum_i tanh(hid[row][i]) * Ws2[i]
__global__ __launch_bounds__(256) void sself_reduce(const float* __restrict__ hid,
                                                    const float* __restrict__ Ws2,
                                                    const float* __restrict__ Ws2b,
                                                    float* __restrict__ s_self) {
  int row = blockIdx.x * 4 + (threadIdx.x >> 6);
  int lane = threadIdx.x & 63;
  float acc = 0.f;
  for (int i = lane; i < 150; i += 64) acc += tanhf(hid[(long)row * 160 + i]) * Ws2[i];
#pragma unroll
  for (int o = 32; o > 0; o >>= 1) acc += __shfl_down(acc, o, 64);
  if (lane == 0) s_self[row] = acc + Ws2b[0];
}

// =============== dec_inp: prefix-scan softmax -> dec hi/lo (split) + xcat ===============
__global__ __launch_bounds__(256) void decinp2_kernel(const float* __restrict__ input,
                                                      const float* __restrict__ s_self,
                                                      u16* __restrict__ dec_hi,
                                                      u16* __restrict__ dec_lo,
                                                      u16* __restrict__ xcat) {
  __shared__ float x[ND * NEMB];  // 38.4 KB
  __shared__ float ew[ND], invD[ND];
  const int b = blockIdx.x, tid = threadIdx.x;
  const float4* src = (const float4*)(input + (long)b * ND * NEMB);
  for (int i = tid; i < ND * NEMB / 4; i += 256) ((float4*)x)[i] = src[i];
  if (tid == 0) {
    float M = -1e30f;
    for (int u = 0; u < ND; u++) M = fmaxf(M, s_self[b * ND + u]);
    float s = 0.f;
    for (int u = 0; u < ND; u++) {
      float e = expf(s_self[b * ND + u] - M);
      ew[u] = e; s += e; invD[u] = 1.f / s;
    }
  }
  __syncthreads();
  for (int e = tid; e < NEMB; e += 256) {
    float acc = 0.f;
    for (int u = 0; u < ND; u++) {
      acc = fmaf(ew[u], x[u * NEMB + e], acc);
      float d = acc * invD[u];
      const long row = (long)u * NB + b;
      u16 hv = f2bf(d);
      dec_hi[row * 320 + e] = hv;
      dec_lo[row * 320 + e] = f2bf(d - bf2f(hv));
      xcat[row * 832 + e] = hv;
    }
  }
  for (int idx = tid; idx < ND * 20; idx += 256) {
    int u = idx / 20, e = 300 + idx % 20;
    const long row = (long)u * NB + b;
    dec_hi[row * 320 + e] = 0;
    dec_lo[row * 320 + e] = 0;
    xcat[row * 832 + 512 + e] = 0;  // K-pad cols 812..831
  }
}

// =============== enc-softmax + x_att -> bf16 into xcat[300..811] & hcat[512..1023] ===============
__global__ __launch_bounds__(256) void xatt_kernel(const float* __restrict__ enc_dot,
                                                   const float* __restrict__ enc,
                                                   u16* __restrict__ xcat,
                                                   u16* __restrict__ hcat) {
  __shared__ float al[NTE][ND + 1];
  int b = blockIdx.x, tid = threadIdx.x;
  for (int i = tid; i < NTE * ND; i += 256) al[i >> 5][i & 31] = enc_dot[(long)b * NTE * ND + i];
  __syncthreads();
  if (tid < ND) {
    int t = tid;
    float m = -1e30f;
    for (int tp = 0; tp < NTE; tp++) m = fmaxf(m, al[tp][t]);
    float s = 0.f;
    for (int tp = 0; tp < NTE; tp++) { float e = expf(al[tp][t] - m); al[tp][t] = e; s += e; }
    float inv = 1.f / s;
    for (int tp = 0; tp < NTE; tp++) al[tp][t] *= inv;
  }
  __syncthreads();
  int tx = tid & 31, ty = tid >> 5;
  const float* eb = enc + (long)b * NTE * NH;
  for (int hc = 0; hc < NH; hc += 128) {
    float acc[4][4] = {};
    for (int tp = 0; tp < NTE; tp++) {
      float4 ev = *(const float4*)(eb + (long)tp * NH + hc + (tx << 2));
#pragma unroll
      for (int i = 0; i < 4; i++) {
        float a = al[tp][(ty << 2) + i];
        acc[i][0] = fmaf(a, ev.x, acc[i][0]);
        acc[i][1] = fmaf(a, ev.y, acc[i][1]);
        acc[i][2] = fmaf(a, ev.z, acc[i][2]);
        acc[i][3] = fmaf(a, ev.w, acc[i][3]);
      }
    }
#pragma unroll
    for (int i = 0; i < 4; i++) {
      const long row = (long)((ty << 2) + i) * NB + b;
      const int h = hc + (tx << 2);
      ushort4 u;
      u.x = f2bf(acc[i][0]); u.y = f2bf(acc[i][1]);
      u.z = f2bf(acc[i][2]); u.w = f2bf(acc[i][3]);
      *(ushort4*)(xcat + row * 832 + 300 + h) = u;
      *(ushort4*)(hcat + row * 1024 + 512 + h) = u;
    }
  }
}

// =============== host ===============
extern "C" void kernel_launch(void* const* d_in, const int* in_sizes, int n_in,
                              void* d_out, int out_size, void* d_ws, size_t ws_size,
                              hipStream_t stream) {
  const float* input = (const float*)d_in[0];
  const float* enc   = (const float*)d_in[1];
  const float* h0   = (const float*)d_in[3];
  const float* c0   = (const float*)d_in[4];
  const float* Watt = (const float*)d_in[5];
  const float* Wv   = (const float*)d_in[7];
  const float* Wvb  = (const float*)d_in[8];
  const float* Ws1  = (const float*)d_in[9];
  const float* Ws1b = (const float*)d_in[10];
  const float* Ws2  = (const float*)d_in[11];
  const float* Ws2b = (const float*)d_in[12];
  const float* vmat = (const float*)d_in[13];
  const float* Wih  = (const float*)d_in[14];
  const float* Whh  = (const float*)d_in[15];
  const float* bih  = (const float*)d_in[16];
  const float* bhh  = (const float*)d_in[17];
  float* out = (float*)d_out;

  // workspace (float units, 16-float aligned)
  float* base = (float*)d_ws;
  size_t off = 0;
  auto alloc = [&](size_t n) { float* p = base + off; off += (n + 15) & ~15ull; return p; };
  u16* vnorm_bf = (u16*)alloc((size_t)5120 * 320 / 2);
  u16* wae_hi   = (u16*)alloc((size_t)512 * 320 / 2);
  u16* wae_lo   = (u16*)alloc((size_t)512 * 320 / 2);
  u16* wih_bf   = (u16*)alloc((size_t)2048 * 832 / 2);
  u16* whh_bf   = (u16*)alloc((size_t)2048 * 512 / 2);
  u16* wv_bf    = (u16*)alloc((size_t)384 * 1024 / 2);
  u16* ws1_bf   = (u16*)alloc((size_t)256 * 320 / 2);
  float* bsumv  = alloc(4 * NH);
  float* s_self = alloc(NB * ND);
  u16* dec_hi   = (u16*)alloc((size_t)ND * NB * 320 / 2);
  u16* dec_lo   = (u16*)alloc((size_t)ND * NB * 320 / 2);
  u16* xcat     = (u16*)alloc((size_t)ND * NB * 832 / 2);
  u16* hcat     = (u16*)alloc((size_t)ND * NB * 1024 / 2);
  u16* hi2_bf   = (u16*)alloc((size_t)ND * NB * 320 / 2);
  u16* h0_bf    = (u16*)alloc((size_t)NB * NH / 2);
  float* c_buf  = alloc((size_t)NB * NH);
  float* region = alloc((size_t)ND * NB * 4 * NH);  // 16.78M floats, overlaid:
  u16* wdec_hi  = (u16*)region;                      // [8192][512] u16 (floats 0..2.10M)
  u16* wdec_lo  = (u16*)(region + 2097152);          // [8192][512] u16 (2.10M..4.19M)
  float* enc_dot = region + 4194304;                 // [b][128][32] f32 (4.19M..5.24M)
  u16*   in_bf   = (u16*)(region + 6000000);         // [8192][320] bf16, dead after hid gemm
  float* hid     = region + 7500000;                 // [8192][160] f32, dead after sself_reduce
  u16*   inp_g   = (u16*)region;                     // [8192][2048] bf16, written after all die

  auto mg = [&](MGP p, int gm, int gn) { mg_gemm<<<dim3(gm, gn), 256, 0, stream>>>(p); };

  prep_all<<<(int)((PREP_TOT + 255) / 256), 256, 0, stream>>>(
      input, Ws1, Wih, Whh, Wv, Watt, bih, bhh, h0, c0,
      in_bf, ws1_bf, wih_bf, whh_bf, wv_bf, wae_hi, wae_lo, bsumv, h0_bf, c_buf);
  vnorm_kernel<<<5120, 64, 0, stream>>>(vmat, vnorm_bf);

  {  // hid = input-tanh GEMM: [8192][320] @ [256][320]^T -> fp32 [8192][160-strided], +Ws1b
    MGP p{};
    p.A = in_bf; p.lda = 320; p.B = ws1_bf; p.ldb = 320;
    p.D = hid; p.rbs = 30; p.s1 = 160; p.s2 = 0;
    p.bias = Ws1b; p.N = 150; p.K = 320;
    mg(p, 64, 2);
  }
  sself_reduce<<<2048, 256, 0, stream>>>(hid, Ws2, Ws2b, s_self);
  decinp2_kernel<<<NB, 256, 0, stream>>>(input, s_self, dec_hi, dec_lo, xcat);

  {  // wdec (split-bf16, 3 pairs, one dispatch): emits wdec hi/lo [8192][512]
    MGP p{};
    p.A = dec_hi; p.lda = 320; p.B = wae_hi; p.ldb = 320;
    p.A2 = dec_hi; p.B2 = wae_lo;
    p.A3 = dec_lo; p.B3 = wae_hi;
    p.rbs = 30;
    p.Dbf = wdec_hi; p.Dbf2 = wdec_lo; p.ldbf = 512; p.padN = 512;
    p.N = 512; p.K = 320;
    mg(p, 64, 4);
  }
  // enc_dot[b] = enc[b] @ wdec[:,b,:]^T (split-bf16 MFMA, in-register enc conversion)
  encdot_kernel<<<NB, 256, 0, stream>>>(enc, wdec_hi, wdec_lo, enc_dot);
  xatt_kernel<<<NB, 256, 0, stream>>>(enc_dot, enc, xcat, hcat);

  {  // inp_gates (gate-interleaved cols, bf16 out) = xcat @ WihP^T + biasP   [8192][2048]
    MGP p{};
    p.A = xcat; p.lda = 832; p.B = wih_bf; p.ldb = 832;
    p.rbs = 30;
    p.Dbf = inp_g; p.ldbf = 2048; p.padN = 2048;
    p.bias = bsumv; p.N = 2048; p.K = 832;
    mg(p, 64, 16);
  }

  // recurrence: one launch per step, 128 blocks (batch x j partition, no cross-block deps)
  for (int t = 0; t < ND; t++) {
    const u16* hp = (t == 0) ? h0_bf : (hcat + (size_t)(t - 1) * NB * 1024);
    long ldh = (t == 0) ? NH : 1024;
    step_lstm2<<<dim3(4, 32), 256, 0, stream>>>(hp, ldh, whh_bf,
                                                inp_g + (size_t)t * NB * 2048, c_buf,
                                                hcat + (size_t)t * NB * 1024);
  }

  {  // hi2 = [h|x_att] @ Wv^T + Wvb -> bf16 [8192][320]
    MGP p{};
    p.A = hcat; p.lda = 1024; p.B = wv_bf; p.ldb = 1024;
    p.rbs = 30;
    p.Dbf = hi2_bf; p.ldbf = 320; p.padN = 320;
    p.bias = Wvb; p.N = 300; p.K = 1024;
    mg(p, 64, 3);
  }
  {  // logits: out[b][t][v] = hi2 . v_norm  (row = t*256+b -> b*s1 + t*s2)
    MGP p{};
    p.A = hi2_bf; p.lda = 320; p.B = vnorm_bf; p.ldb = 320;
    p.D = out; p.rbs = 8; p.s1 = (long)ND * NV; p.s2 = NV;
    p.N = NV; p.K = 320;
    mg(p, 64, 40);
  }
}

// Round 16
// 595.165 us; speedup vs baseline: 1.0211x; 1.0013x over previous
//
#include <hip/hip_runtime.h>

// Problem dims
#define NB 256    // batch
#define ND 32     // T_dec
#define NTE 128   // T_enc
#define NH 512    // hidden
#define NEMB 300  // E
#define NV 5000   // vocab

typedef unsigned short u16;
typedef __attribute__((ext_vector_type(8))) short bf16x8;
typedef __attribute__((ext_vector_type(4))) float f32x4;

__device__ __forceinline__ float sigm(float x) { return 1.f / (1.f + expf(-x)); }

__device__ __forceinline__ u16 f2bf(float x) {
  union { float f; unsigned u; } v; v.f = x;
  unsigned r = v.u + 0x7fffu + ((v.u >> 16) & 1u);
  return (u16)(r >> 16);
}
__device__ __forceinline__ float bf2f(u16 h) {
  union { unsigned u; float f; } v; v.u = ((unsigned)h) << 16; return v.f;
}

#define GLOBAL_AS __attribute__((address_space(1)))
#define LDS_AS __attribute__((address_space(3)))
__device__ __forceinline__ void g2l16(const void* g, void* l) {
  __builtin_amdgcn_global_load_lds((GLOBAL_AS void*)g, (LDS_AS void*)l, 16, 0, 0);
}

// =============== bf16 MFMA NT GEMM: D = sum_pairs A_p @ B_p^T (+bias) ===============
// Up to 3 (A,B) pairs (same lda/ldb/K) accumulate into one acc (split-bf16 path).
// Double-buffered LDS prefetch pipeline (T3 minimum 2-phase): stage tile t+1 before
// computing tile t; counted vmcnt(4) + raw s_barrier (no full __syncthreads drain).
// Scalar epilogue (R12 known-good; the vectorized LDS-transpose epilogue of R13-R15
// was replay-nondeterministic and is intentionally NOT used).
// fp32 out: off = (row & msk)*s1 + (row>>rbs)*s2 + n. bf16 out: hi (Dbf) + optional lo (Dbf2).
struct MGP {
  const u16* A; long lda;
  const u16* B; long ldb;
  const u16* A2; const u16* B2;
  const u16* A3; const u16* B3;
  float* D; int rbs; long s1, s2;
  u16* Dbf; u16* Dbf2; long ldbf; int padN;
  const float* bias;
  int N, K;
};

__global__ __launch_bounds__(256) void mg_gemm(MGP p) {
  __shared__ __align__(16) u16 As[2][128 * 32];
  __shared__ __align__(16) u16 Bs[2][128 * 32];
  const int tid = threadIdx.x;
  const int l = tid & 63, w = tid >> 6;
  const int m0 = blockIdx.x * 128, n0 = blockIdx.y * 128;
  const int r4 = l >> 2, c8 = (l & 3) << 3;
  const int wm = (w >> 1) * 64, wn = (w & 1) * 64;

  const u16* Aps[3] = {p.A, p.A2, p.A3};
  const u16* Bps[3] = {p.B, p.B2, p.B3};
  const int npair = p.A3 ? 3 : (p.A2 ? 2 : 1);
  const int kt = p.K >> 5;
  const int T = npair * kt;

  int prn = 0, k0n = 0;  // next tile to stage
  auto stage = [&](int buf) {
    const u16* Abase = Aps[prn] + (long)m0 * p.lda + k0n;
    const u16* Bbase = Bps[prn] + (long)n0 * p.ldb + k0n;
#pragma unroll
    for (int c = 0; c < 2; ++c) {
      const int rb0 = c * 64 + w * 16;
      g2l16(Abase + (long)(rb0 + r4) * p.lda + c8, &As[buf][rb0 * 32]);
      g2l16(Bbase + (long)(rb0 + r4) * p.ldb + c8, &Bs[buf][rb0 * 32]);
    }
    k0n += 32;
    if (k0n >= p.K) { k0n = 0; ++prn; }
  };

  f32x4 acc[4][4] = {};
  stage(0);  // prologue: tile 0 in flight (4 g2l16/thread)

#pragma unroll 1
  for (int t = 0; t < T; ++t) {
    const int cur = t & 1;
    if (t + 1 < T) {
      stage(cur ^ 1);  // issue next tile (4 more ops in flight)
      asm volatile("s_waitcnt vmcnt(4)" ::: "memory");  // tile t's loads landed
    } else {
      asm volatile("s_waitcnt vmcnt(0)" ::: "memory");
    }
    __builtin_amdgcn_s_barrier();        // all threads' tile-t loads landed
    __builtin_amdgcn_sched_barrier(0);   // rule #18: no ds_read hoisting above barrier
    bf16x8 af[4], bfv[4];
#pragma unroll
    for (int f = 0; f < 4; ++f) {
      af[f]  = *(const bf16x8*)&As[cur][(wm + f * 16 + (l & 15)) * 32 + ((l >> 4) << 3)];
      bfv[f] = *(const bf16x8*)&Bs[cur][(wn + f * 16 + (l & 15)) * 32 + ((l >> 4) << 3)];
    }
#pragma unroll
    for (int i = 0; i < 4; ++i)
#pragma unroll
      for (int j = 0; j < 4; ++j)
        acc[i][j] = __builtin_amdgcn_mfma_f32_16x16x32_bf16(af[i], bfv[j], acc[i][j], 0, 0, 0);
    __builtin_amdgcn_s_barrier();        // reads done (reg-delivered) before buf reuse
  }

  const int cc = l & 15, cr = (l >> 4) << 2;
  const long msk = ((long)1 << p.rbs) - 1;
#pragma unroll
  for (int fn = 0; fn < 4; ++fn) {
    const int n = n0 + wn + fn * 16 + cc;
    const bool nok = n < p.N;
    const float badd = (p.bias && nok) ? p.bias[n] : 0.f;
#pragma unroll
    for (int fm = 0; fm < 4; ++fm) {
#pragma unroll
      for (int j = 0; j < 4; ++j) {
        const long row = m0 + wm + fm * 16 + cr + j;
        float v = acc[fm][fn][j] + badd;
        if (p.D && nok)
          p.D[(row & msk) * p.s1 + (row >> p.rbs) * p.s2 + n] = v;
        if (p.Dbf && n < p.padN) {
          u16 hv = nok ? f2bf(v) : (u16)0;
          p.Dbf[row * p.ldbf + n] = hv;
          if (p.Dbf2)
            p.Dbf2[row * p.ldbf + n] = nok ? f2bf(v - bf2f(hv)) : (u16)0;
        }
      }
    }
  }
}

// =============== batched enc_dot (split-bf16 MFMA): ed[b] = enc[b] @ wdec[:,b,:]^T ===============
__global__ __launch_bounds__(256) void encdot_kernel(const float* __restrict__ enc,
                                                     const u16* __restrict__ wh,
                                                     const u16* __restrict__ wl,
                                                     float* __restrict__ ed) {
  const int b = blockIdx.x;
  const int tid = threadIdx.x, l = tid & 63, w = tid >> 6;
  const int m0 = w * 32;
  const int lr = l & 15, lk = l >> 4;
  const float* eb = enc + (long)b * NTE * NH;
  f32x4 acc[2][2] = {};

#pragma unroll 1
  for (int ks = 0; ks < 16; ++ks) {
    const int k0 = ks * 32 + lk * 8;
    bf16x8 ah[2], alo[2];
#pragma unroll
    for (int mi = 0; mi < 2; ++mi) {
      const float* src = eb + (long)(m0 + mi * 16 + lr) * NH + k0;
      float4 x0 = *(const float4*)(src);
      float4 x1 = *(const float4*)(src + 4);
      float xs[8] = {x0.x, x0.y, x0.z, x0.w, x1.x, x1.y, x1.z, x1.w};
      bf16x8 h, lo;
#pragma unroll
      for (int q = 0; q < 8; ++q) {
        u16 hv = f2bf(xs[q]);
        h[q] = (short)hv;
        lo[q] = (short)f2bf(xs[q] - bf2f(hv));
      }
      ah[mi] = h; alo[mi] = lo;
    }
#pragma unroll
    for (int ni = 0; ni < 2; ++ni) {
      const long brow = ((long)(ni * 16 + lr) * NB + b) * 512 + k0;
      bf16x8 bh = *(const bf16x8*)(wh + brow);
      bf16x8 bl = *(const bf16x8*)(wl + brow);
#pragma unroll
      for (int mi = 0; mi < 2; ++mi) {
        acc[mi][ni] = __builtin_amdgcn_mfma_f32_16x16x32_bf16(ah[mi], bh, acc[mi][ni], 0, 0, 0);
        acc[mi][ni] = __builtin_amdgcn_mfma_f32_16x16x32_bf16(ah[mi], bl, acc[mi][ni], 0, 0, 0);
        acc[mi][ni] = __builtin_amdgcn_mfma_f32_16x16x32_bf16(alo[mi], bh, acc[mi][ni], 0, 0, 0);
      }
    }
  }

  const int cr = lk << 2;
  float* edb = ed + (long)b * NTE * ND;
#pragma unroll
  for (int mi = 0; mi < 2; ++mi)
#pragma unroll
    for (int ni = 0; ni < 2; ++ni)
#pragma unroll
      for (int j = 0; j < 4; ++j)
        edb[(long)(m0 + mi * 16 + cr + j) * ND + ni * 16 + lr] = acc[mi][ni][j];
}

// =============== per-step LSTM: grid (4 bg, 32 jg), block 256 = 4 waves ===============
// Kernel boundary = device-wide barrier (cheapest on 8 non-coherent XCDs; R8 lesson).
// G is bf16 gate-interleaved: 8B (4 gates) per (b,j).
__global__ __launch_bounds__(256) void step_lstm2(const u16* __restrict__ hprev, long ldh,
                                                  const u16* __restrict__ whh,
                                                  const u16* __restrict__ Gt,
                                                  float* __restrict__ c,
                                                  u16* __restrict__ hout) {
  __shared__ __align__(16) u16 WhhS[64 * 512];  // 64KB
  const int tid = threadIdx.x, l = tid & 63, w = tid >> 6;
  const int mb = blockIdx.x * 64, j0 = blockIdx.y * 16;

#pragma unroll
  for (int it = 0; it < 16; ++it) {
    const int row = it * 4 + w;
    const int g = row >> 4, r = row & 15;
    const long goff = ((long)(g * 512 + j0 + r)) * 512 + ((l ^ (row & 7)) << 3);
    g2l16(whh + goff, &WhhS[row * 512]);
  }

  bf16x8 av[16];
  const u16* hb = hprev + (long)(mb + w * 16 + (l & 15)) * ldh + ((l >> 4) << 3);
#pragma unroll
  for (int ks = 0; ks < 16; ++ks) av[ks] = *(const bf16x8*)(hb + ks * 32);

  __syncthreads();

  f32x4 acc[4] = {};
#pragma unroll
  for (int ks = 0; ks < 16; ++ks) {
#pragma unroll
    for (int g = 0; g < 4; ++g) {
      const int row = g * 16 + (l & 15);
      const int cl = (ks * 4 + (l >> 4)) ^ (l & 7);
      bf16x8 bv = *(const bf16x8*)((const char*)WhhS + row * 1024 + (cl << 4));
      acc[g] = __builtin_amdgcn_mfma_f32_16x16x32_bf16(av[ks], bv, acc[g], 0, 0, 0);
    }
  }

  const int j = j0 + (l & 15);
  const int bb = mb + w * 16 + ((l >> 4) << 2);
#pragma unroll
  for (int jr = 0; jr < 4; ++jr) {
    const int b = bb + jr;
    ushort4 gv = *(const ushort4*)(Gt + (long)b * 2048 + j * 4);  // {i,f,g,o} bf16
    float ig = sigm(acc[0][jr] + bf2f(gv.x));
    float fg = sigm(acc[1][jr] + bf2f(gv.y));
    float gg = tanhf(acc[2][jr] + bf2f(gv.z));
    float og = sigm(acc[3][jr] + bf2f(gv.w));
    const long ci = (long)b * NH + j;
    float cn = fg * c[ci] + ig * gg;
    c[ci] = cn;
    hout[(long)b * 1024 + j] = f2bf(og * tanhf(cn));
  }
}

// =============== v_norm rows -> bf16 [5120][320] (zero-padded) ===============
__global__ void vnorm_kernel(const float* __restrict__ v, u16* __restrict__ vn) {
  int r = blockIdx.x, tid = threadIdx.x;
  if (r >= NV) {
    for (int e = tid; e < 320; e += 64) vn[(long)r * 320 + e] = 0;
    return;
  }
  float ss = 0.f;
  for (int e = tid; e < NEMB; e += 64) { float x = v[(long)r * NEMB + e]; ss += x * x; }
#pragma unroll
  for (int o = 32; o > 0; o >>= 1) ss += __shfl_down(ss, o, 64);
  ss = __shfl(ss, 0, 64);
  float sc = 1.f / fmaxf(sqrtf(ss), 1e-12f);
  for (int e = tid; e < 320; e += 64)
    vn[(long)r * 320 + e] = (e < NEMB) ? f2bf(v[(long)r * NEMB + e] * sc) : (u16)0;
}

// =============== fused prep ===============
#define SEG_A 2621440L   // in_bf [8192][320]
#define SEG_B 81920L     // ws1_bf [256][320]
#define SEG_C 1703936L   // wih_bf [2048][832] gate-interleaved rows
#define SEG_D 1048576L   // whh_bf [2048][512]
#define SEG_E 393216L    // wv_bf [384][1024]
#define SEG_F 163840L    // wae hi/lo [512][320]
#define SEG_G 2048L      // bsumv gate-interleaved
#define SEG_H 131072L    // h0_bf
#define SEG_I 131072L    // c_buf = c0 copy
#define PREP_TOT (SEG_A + SEG_B + SEG_C + SEG_D + SEG_E + SEG_F + SEG_G + SEG_H + SEG_I)

__global__ void prep_all(const float* __restrict__ input, const float* __restrict__ Ws1,
                         const float* __restrict__ Wih, const float* __restrict__ Whh,
                         const float* __restrict__ Wv, const float* __restrict__ Watt,
                         const float* __restrict__ bih, const float* __restrict__ bhh,
                         const float* __restrict__ h0, const float* __restrict__ c0,
                         u16* __restrict__ in_bf, u16* __restrict__ ws1_bf,
                         u16* __restrict__ wih_bf, u16* __restrict__ whh_bf,
                         u16* __restrict__ wv_bf, u16* __restrict__ wae_hi,
                         u16* __restrict__ wae_lo,
                         float* __restrict__ bsumv, u16* __restrict__ h0_bf,
                         float* __restrict__ c_buf) {
  long idx = (long)blockIdx.x * 256 + threadIdx.x;
  if (idx < SEG_A) {
    int row = (int)(idx / 320), e = (int)(idx % 320);
    in_bf[idx] = (e < NEMB) ? f2bf(input[(long)row * NEMB + e]) : (u16)0;
    return;
  }
  idx -= SEG_A;
  if (idx < SEG_B) {
    int r = (int)(idx / 320), e = (int)(idx % 320);
    ws1_bf[idx] = (r < 150 && e < NEMB) ? f2bf(Ws1[r * NEMB + e]) : (u16)0;
    return;
  }
  idx -= SEG_B;
  if (idx < SEG_C) {
    int rp = (int)(idx / 832), cpos = (int)(idx % 832);
    int g = rp & 3, j = rp >> 2;
    wih_bf[idx] = (cpos < 812) ? f2bf(Wih[(long)(g * 512 + j) * 812 + cpos]) : (u16)0;
    return;
  }
  idx -= SEG_C;
  if (idx < SEG_D) { whh_bf[idx] = f2bf(Whh[idx]); return; }
  idx -= SEG_D;
  if (idx < SEG_E) {
    int r = (int)(idx >> 10);
    wv_bf[idx] = (r < NEMB) ? f2bf(Wv[idx]) : (u16)0;
    return;
  }
  idx -= SEG_E;
  if (idx < SEG_F) {  // wae hi/lo split
    int k = (int)(idx / 320), e = (int)(idx % 320);
    float x = (e < NEMB) ? Watt[(long)e * 1024 + 512 + k] : 0.f;
    u16 hv = f2bf(x);
    wae_hi[idx] = hv;
    wae_lo[idx] = f2bf(x - bf2f(hv));
    return;
  }
  idx -= SEG_F;
  if (idx < SEG_G) {
    int g = (int)(idx & 3), j = (int)(idx >> 2);
    bsumv[idx] = bih[g * 512 + j] + bhh[g * 512 + j];
    return;
  }
  idx -= SEG_G;
  if (idx < SEG_H) { h0_bf[idx] = f2bf(h0[idx]); return; }
  idx -= SEG_H;
  if (idx < SEG_I) c_buf[idx] = c0[idx];
}

// s_self[row] = Ws2b + sum_i tanh(hid[row][i]) * Ws2[i]
__global__ __launch_bounds__(256) void sself_reduce(const float* __restrict__ hid,
                                                    const float* __restrict__ Ws2,
                                                    const float* __restrict__ Ws2b,
                                                    float* __restrict__ s_self) {
  int row = blockIdx.x * 4 + (threadIdx.x >> 6);
  int lane = threadIdx.x & 63;
  float acc = 0.f;
  for (int i = lane; i < 150; i += 64) acc += tanhf(hid[(long)row * 160 + i]) * Ws2[i];
#pragma unroll
  for (int o = 32; o > 0; o >>= 1) acc += __shfl_down(acc, o, 64);
  if (lane == 0) s_self[row] = acc + Ws2b[0];
}

// =============== dec_inp: prefix-scan softmax -> dec hi/lo (split) + xcat ===============
__global__ __launch_bounds__(256) void decinp2_kernel(const float* __restrict__ input,
                                                      const float* __restrict__ s_self,
                                                      u16* __restrict__ dec_hi,
                                                      u16* __restrict__ dec_lo,
                                                      u16* __restrict__ xcat) {
  __shared__ float x[ND * NEMB];  // 38.4 KB
  __shared__ float ew[ND], invD[ND];
  const int b = blockIdx.x, tid = threadIdx.x;
  const float4* src = (const float4*)(input + (long)b * ND * NEMB);
  for (int i = tid; i < ND * NEMB / 4; i += 256) ((float4*)x)[i] = src[i];
  if (tid == 0) {
    float M = -1e30f;
    for (int u = 0; u < ND; u++) M = fmaxf(M, s_self[b * ND + u]);
    float s = 0.f;
    for (int u = 0; u < ND; u++) {
      float e = expf(s_self[b * ND + u] - M);
      ew[u] = e; s += e; invD[u] = 1.f / s;
    }
  }
  __syncthreads();
  for (int e = tid; e < NEMB; e += 256) {
    float acc = 0.f;
    for (int u = 0; u < ND; u++) {
      acc = fmaf(ew[u], x[u * NEMB + e], acc);
      float d = acc * invD[u];
      const long row = (long)u * NB + b;
      u16 hv = f2bf(d);
      dec_hi[row * 320 + e] = hv;
      dec_lo[row * 320 + e] = f2bf(d - bf2f(hv));
      xcat[row * 832 + e] = hv;
    }
  }
  for (int idx = tid; idx < ND * 20; idx += 256) {
    int u = idx / 20, e = 300 + idx % 20;
    const long row = (long)u * NB + b;
    dec_hi[row * 320 + e] = 0;
    dec_lo[row * 320 + e] = 0;
    xcat[row * 832 + 512 + e] = 0;  // K-pad cols 812..831
  }
}

// =============== enc-softmax + x_att -> bf16 into xcat[300..811] & hcat[512..1023] ===============
__global__ __launch_bounds__(256) void xatt_kernel(const float* __restrict__ enc_dot,
                                                   const float* __restrict__ enc,
                                                   u16* __restrict__ xcat,
                                                   u16* __restrict__ hcat) {
  __shared__ float al[NTE][ND + 1];
  int b = blockIdx.x, tid = threadIdx.x;
  for (int i = tid; i < NTE * ND; i += 256) al[i >> 5][i & 31] = enc_dot[(long)b * NTE * ND + i];
  __syncthreads();
  if (tid < ND) {
    int t = tid;
    float m = -1e30f;
    for (int tp = 0; tp < NTE; tp++) m = fmaxf(m, al[tp][t]);
    float s = 0.f;
    for (int tp = 0; tp < NTE; tp++) { float e = expf(al[tp][t] - m); al[tp][t] = e; s += e; }
    float inv = 1.f / s;
    for (int tp = 0; tp < NTE; tp++) al[tp][t] *= inv;
  }
  __syncthreads();
  int tx = tid & 31, ty = tid >> 5;
  const float* eb = enc + (long)b * NTE * NH;
  for (int hc = 0; hc < NH; hc += 128) {
    float acc[4][4] = {};
    for (int tp = 0; tp < NTE; tp++) {
      float4 ev = *(const float4*)(eb + (long)tp * NH + hc + (tx << 2));
#pragma unroll
      for (int i = 0; i < 4; i++) {
        float a = al[tp][(ty << 2) + i];
        acc[i][0] = fmaf(a, ev.x, acc[i][0]);
        acc[i][1] = fmaf(a, ev.y, acc[i][1]);
        acc[i][2] = fmaf(a, ev.z, acc[i][2]);
        acc[i][3] = fmaf(a, ev.w, acc[i][3]);
      }
    }
#pragma unroll
    for (int i = 0; i < 4; i++) {
      const long row = (long)((ty << 2) + i) * NB + b;
      const int h = hc + (tx << 2);
      ushort4 u;
      u.x = f2bf(acc[i][0]); u.y = f2bf(acc[i][1]);
      u.z = f2bf(acc[i][2]); u.w = f2bf(acc[i][3]);
      *(ushort4*)(xcat + row * 832 + 300 + h) = u;
      *(ushort4*)(hcat + row * 1024 + 512 + h) = u;
    }
  }
}

// =============== host ===============
extern "C" void kernel_launch(void* const* d_in, const int* in_sizes, int n_in,
                              void* d_out, int out_size, void* d_ws, size_t ws_size,
                              hipStream_t stream) {
  const float* input = (const float*)d_in[0];
  const float* enc   = (const float*)d_in[1];
  const float* h0   = (const float*)d_in[3];
  const float* c0   = (const float*)d_in[4];
  const float* Watt = (const float*)d_in[5];
  const float* Wv   = (const float*)d_in[7];
  const float* Wvb  = (const float*)d_in[8];
  const float* Ws1  = (const float*)d_in[9];
  const float* Ws1b = (const float*)d_in[10];
  const float* Ws2  = (const float*)d_in[11];
  const float* Ws2b = (const float*)d_in[12];
  const float* vmat = (const float*)d_in[13];
  const float* Wih  = (const float*)d_in[14];
  const float* Whh  = (const float*)d_in[15];
  const float* bih  = (const float*)d_in[16];
  const float* bhh  = (const float*)d_in[17];
  float* out = (float*)d_out;

  // workspace (float units, 16-float aligned)
  float* base = (float*)d_ws;
  size_t off = 0;
  auto alloc = [&](size_t n) { float* p = base + off; off += (n + 15) & ~15ull; return p; };
  u16* vnorm_bf = (u16*)alloc((size_t)5120 * 320 / 2);
  u16* wae_hi   = (u16*)alloc((size_t)512 * 320 / 2);
  u16* wae_lo   = (u16*)alloc((size_t)512 * 320 / 2);
  u16* wih_bf   = (u16*)alloc((size_t)2048 * 832 / 2);
  u16* whh_bf   = (u16*)alloc((size_t)2048 * 512 / 2);
  u16* wv_bf    = (u16*)alloc((size_t)384 * 1024 / 2);
  u16* ws1_bf   = (u16*)alloc((size_t)256 * 320 / 2);
  float* bsumv  = alloc(4 * NH);
  float* s_self = alloc(NB * ND);
  u16* dec_hi   = (u16*)alloc((size_t)ND * NB * 320 / 2);
  u16* dec_lo   = (u16*)alloc((size_t)ND * NB * 320 / 2);
  u16* xcat     = (u16*)alloc((size_t)ND * NB * 832 / 2);
  u16* hcat     = (u16*)alloc((size_t)ND * NB * 1024 / 2);
  u16* hi2_bf   = (u16*)alloc((size_t)ND * NB * 320 / 2);
  u16* h0_bf    = (u16*)alloc((size_t)NB * NH / 2);
  float* c_buf  = alloc((size_t)NB * NH);
  float* region = alloc((size_t)ND * NB * 4 * NH);  // 16.78M floats, overlaid:
  u16* wdec_hi  = (u16*)region;                      // [8192][512] u16 (floats 0..2.10M)
  u16* wdec_lo  = (u16*)(region + 2097152);          // [8192][512] u16 (2.10M..4.19M)
  float* enc_dot = region + 4194304;                 // [b][128][32] f32 (4.19M..5.24M)
  u16*   in_bf   = (u16*)(region + 6000000);         // [8192][320] bf16, dead after hid gemm
  float* hid     = region + 7500000;                 // [8192][160] f32, dead after sself_reduce
  u16*   inp_g   = (u16*)region;                     // [8192][2048] bf16, written after all die

  auto mg = [&](MGP p, int gm, int gn) { mg_gemm<<<dim3(gm, gn), 256, 0, stream>>>(p); };

  prep_all<<<(int)((PREP_TOT + 255) / 256), 256, 0, stream>>>(
      input, Ws1, Wih, Whh, Wv, Watt, bih, bhh, h0, c0,
      in_bf, ws1_bf, wih_bf, whh_bf, wv_bf, wae_hi, wae_lo, bsumv, h0_bf, c_buf);
  vnorm_kernel<<<5120, 64, 0, stream>>>(vmat, vnorm_bf);

  {  // hid = input-tanh GEMM: [8192][320] @ [256][320]^T -> fp32 [8192][160-strided], +Ws1b
    MGP p{};
    p.A = in_bf; p.lda = 320; p.B = ws1_bf; p.ldb = 320;
    p.D = hid; p.rbs = 30; p.s1 = 160; p.s2 = 0;
    p.bias = Ws1b; p.N = 150; p.K = 320;
    mg(p, 64, 2);
  }
  sself_reduce<<<2048, 256, 0, stream>>>(hid, Ws2, Ws2b, s_self);
  decinp2_kernel<<<NB, 256, 0, stream>>>(input, s_self, dec_hi, dec_lo, xcat);

  {  // wdec (split-bf16, 3 pairs, one dispatch): emits wdec hi/lo [8192][512]
    MGP p{};
    p.A = dec_hi; p.lda = 320; p.B = wae_hi; p.ldb = 320;
    p.A2 = dec_hi; p.B2 = wae_lo;
    p.A3 = dec_lo; p.B3 = wae_hi;
    p.rbs = 30;
    p.Dbf = wdec_hi; p.Dbf2 = wdec_lo; p.ldbf = 512; p.padN = 512;
    p.N = 512; p.K = 320;
    mg(p, 64, 4);
  }
  // enc_dot[b] = enc[b] @ wdec[:,b,:]^T (split-bf16 MFMA, in-register enc conversion)
  encdot_kernel<<<NB, 256, 0, stream>>>(enc, wdec_hi, wdec_lo, enc_dot);
  xatt_kernel<<<NB, 256, 0, stream>>>(enc_dot, enc, xcat, hcat);

  {  // inp_gates (gate-interleaved cols, bf16 out) = xcat @ WihP^T + biasP   [8192][2048]
    MGP p{};
    p.A = xcat; p.lda = 832; p.B = wih_bf; p.ldb = 832;
    p.rbs = 30;
    p.Dbf = inp_g; p.ldbf = 2048; p.padN = 2048;
    p.bias = bsumv; p.N = 2048; p.K = 832;
    mg(p, 64, 16);
  }

  // recurrence: one launch per step, 128 blocks (batch x j partition, no cross-block deps)
  for (int t = 0; t < ND; t++) {
    const u16* hp = (t == 0) ? h0_bf : (hcat + (size_t)(t - 1) * NB * 1024);
    long ldh = (t == 0) ? NH : 1024;
    step_lstm2<<<dim3(4, 32), 256, 0, stream>>>(hp, ldh, whh_bf,
                                                inp_g + (size_t)t * NB * 2048, c_buf,
                                                hcat + (size_t)t * NB * 1024);
  }

  {  // hi2 = [h|x_att] @ Wv^T + Wvb -> bf16 [8192][320]
    MGP p{};
    p.A = hcat; p.lda = 1024; p.B = wv_bf; p.ldb = 1024;
    p.rbs = 30;
    p.Dbf = hi2_bf; p.ldbf = 320; p.padN = 320;
    p.bias = Wvb; p.N = 300; p.K = 1024;
    mg(p, 64, 3);
  }
  {  // logits: out[b][t][v] = hi2 . v_norm  (row = t*256+b -> b*s1 + t*s2)
    MGP p{};
    p.A = hi2_bf; p.lda = 320; p.B = vnorm_bf; p.ldb = 320;
    p.D = out; p.rbs = 8; p.s1 = (long)ND * NV; p.s2 = NV;
    p.N = NV; p.K = 320;
    mg(p, 64, 40);
  }
}

// Round 17
// 574.002 us; speedup vs baseline: 1.0587x; 1.0369x over previous
//
#include <hip/hip_runtime.h>

// Problem dims
#define NB 256    // batch
#define ND 32     // T_dec
#define NTE 128   // T_enc
#define NH 512    // hidden
#define NEMB 300  // E
#define NV 5000   // vocab

typedef unsigned short u16;
typedef __attribute__((ext_vector_type(8))) short bf16x8;
typedef __attribute__((ext_vector_type(4))) float f32x4;
typedef __attribute__((ext_vector_type(16))) float f32x16;

__device__ __forceinline__ float sigm(float x) { return 1.f / (1.f + expf(-x)); }

__device__ __forceinline__ u16 f2bf(float x) {
  union { float f; unsigned u; } v; v.f = x;
  unsigned r = v.u + 0x7fffu + ((v.u >> 16) & 1u);
  return (u16)(r >> 16);
}
__device__ __forceinline__ float bf2f(u16 h) {
  union { unsigned u; float f; } v; v.u = ((unsigned)h) << 16; return v.f;
}

#define GLOBAL_AS __attribute__((address_space(1)))
#define LDS_AS __attribute__((address_space(3)))
__device__ __forceinline__ void g2l16(const void* g, void* l) {
  __builtin_amdgcn_global_load_lds((GLOBAL_AS void*)g, (LDS_AS void*)l, 16, 0, 0);
}

// =============== bf16 MFMA NT GEMM: D = sum_pairs A_p @ B_p^T (+bias) ===============
// (R12 known-good kernel, unchanged.)
struct MGP {
  const u16* A; long lda;
  const u16* B; long ldb;
  const u16* A2; const u16* B2;
  const u16* A3; const u16* B3;
  float* D; int rbs; long s1, s2;
  u16* Dbf; u16* Dbf2; long ldbf; int padN;
  const float* bias;
  int N, K;
};

__global__ __launch_bounds__(256) void mg_gemm(MGP p) {
  __shared__ __align__(16) u16 As[2][128 * 32];
  __shared__ __align__(16) u16 Bs[2][128 * 32];
  const int tid = threadIdx.x;
  const int l = tid & 63, w = tid >> 6;
  const int m0 = blockIdx.x * 128, n0 = blockIdx.y * 128;
  const int r4 = l >> 2, c8 = (l & 3) << 3;
  const int wm = (w >> 1) * 64, wn = (w & 1) * 64;

  const u16* Aps[3] = {p.A, p.A2, p.A3};
  const u16* Bps[3] = {p.B, p.B2, p.B3};
  const int npair = p.A3 ? 3 : (p.A2 ? 2 : 1);
  const int kt = p.K >> 5;
  const int T = npair * kt;

  int prn = 0, k0n = 0;  // next tile to stage
  auto stage = [&](int buf) {
    const u16* Abase = Aps[prn] + (long)m0 * p.lda + k0n;
    const u16* Bbase = Bps[prn] + (long)n0 * p.ldb + k0n;
#pragma unroll
    for (int c = 0; c < 2; ++c) {
      const int rb0 = c * 64 + w * 16;
      g2l16(Abase + (long)(rb0 + r4) * p.lda + c8, &As[buf][rb0 * 32]);
      g2l16(Bbase + (long)(rb0 + r4) * p.ldb + c8, &Bs[buf][rb0 * 32]);
    }
    k0n += 32;
    if (k0n >= p.K) { k0n = 0; ++prn; }
  };

  f32x4 acc[4][4] = {};
  stage(0);  // prologue: tile 0 in flight (4 g2l16/thread)

#pragma unroll 1
  for (int t = 0; t < T; ++t) {
    const int cur = t & 1;
    if (t + 1 < T) {
      stage(cur ^ 1);
      asm volatile("s_waitcnt vmcnt(4)" ::: "memory");
    } else {
      asm volatile("s_waitcnt vmcnt(0)" ::: "memory");
    }
    __builtin_amdgcn_s_barrier();
    __builtin_amdgcn_sched_barrier(0);
    bf16x8 af[4], bfv[4];
#pragma unroll
    for (int f = 0; f < 4; ++f) {
      af[f]  = *(const bf16x8*)&As[cur][(wm + f * 16 + (l & 15)) * 32 + ((l >> 4) << 3)];
      bfv[f] = *(const bf16x8*)&Bs[cur][(wn + f * 16 + (l & 15)) * 32 + ((l >> 4) << 3)];
    }
#pragma unroll
    for (int i = 0; i < 4; ++i)
#pragma unroll
      for (int j = 0; j < 4; ++j)
        acc[i][j] = __builtin_amdgcn_mfma_f32_16x16x32_bf16(af[i], bfv[j], acc[i][j], 0, 0, 0);
    __builtin_amdgcn_s_barrier();
  }

  const int cc = l & 15, cr = (l >> 4) << 2;
  const long msk = ((long)1 << p.rbs) - 1;
#pragma unroll
  for (int fn = 0; fn < 4; ++fn) {
    const int n = n0 + wn + fn * 16 + cc;
    const bool nok = n < p.N;
    const float badd = (p.bias && nok) ? p.bias[n] : 0.f;
#pragma unroll
    for (int fm = 0; fm < 4; ++fm) {
#pragma unroll
      for (int j = 0; j < 4; ++j) {
        const long row = m0 + wm + fm * 16 + cr + j;
        float v = acc[fm][fn][j] + badd;
        if (p.D && nok)
          p.D[(row & msk) * p.s1 + (row >> p.rbs) * p.s2 + n] = v;
        if (p.Dbf && n < p.padN) {
          u16 hv = nok ? f2bf(v) : (u16)0;
          p.Dbf[row * p.ldbf + n] = hv;
          if (p.Dbf2)
            p.Dbf2[row * p.ldbf + n] = nok ? f2bf(v - bf2f(hv)) : (u16)0;
        }
      }
    }
  }
}

// =============== 32x32x16 MFMA NT GEMM (logits only): full-line fp32 writes ===============
// D = A @ B^T. Tile 128x128, 4 waves (2x2 quadrants of 64), each wave 2x2 fragments of
// 32x32. C/D layout: col=lane&31, row=(reg&3)+8*(reg>>2)+4*(lane>>5) -> each scalar
// acc-register store covers 2 FULL 128B lines (no partial-line RMW; fixes the 1.3x
// write amplification without any cross-wave LDS transpose).
// LDS: row-major 64B rows; intra-row 16B-chunk XOR swizzle (chunk ^= row&3) applied on
// BOTH the pre-swizzled global source and the frag reads (rule #21), preserving global
// 64B staging coalescing.
struct MG32 {
  const u16* A; const u16* B;
  float* D; int rbs; long s1, s2;
  int N, K;
};

__global__ __launch_bounds__(256) void mg_gemm32(MG32 p) {
  __shared__ __align__(16) u16 As[2][128 * 32];
  __shared__ __align__(16) u16 Bs[2][128 * 32];
  const int tid = threadIdx.x;
  const int l = tid & 63, w = tid >> 6;
  const int m0 = blockIdx.x * 128, n0 = blockIdx.y * 128;
  const int wm = (w >> 1) * 64, wn = (w & 1) * 64;
  const int r4 = l >> 2;
  const int T = p.K >> 5;

  int k0n = 0;
  auto stage = [&](int buf) {
    const u16* Ab = p.A + (long)m0 * 320 + k0n;
    const u16* Bb = p.B + (long)n0 * 320 + k0n;
#pragma unroll
    for (int cgrp = 0; cgrp < 2; ++cgrp) {
      const int rb0 = cgrp * 64 + w * 16;
      const int row = rb0 + r4;
      const int cs = (((l & 3) ^ (row & 3)) << 3);  // pre-swizzled source chunk
      g2l16(Ab + (long)row * 320 + cs, &As[buf][rb0 * 32]);
      g2l16(Bb + (long)row * 320 + cs, &Bs[buf][rb0 * 32]);
    }
    k0n += 32;
  };

  f32x16 acc[2][2] = {};
  stage(0);

#pragma unroll 1
  for (int t = 0; t < T; ++t) {
    const int cur = t & 1;
    if (t + 1 < T) {
      stage(cur ^ 1);
      asm volatile("s_waitcnt vmcnt(4)" ::: "memory");
    } else {
      asm volatile("s_waitcnt vmcnt(0)" ::: "memory");
    }
    __builtin_amdgcn_s_barrier();
    __builtin_amdgcn_sched_barrier(0);
#pragma unroll
    for (int ks = 0; ks < 2; ++ks) {
      bf16x8 a[2], b[2];
#pragma unroll
      for (int f = 0; f < 2; ++f) {
        const int ra = wm + f * 32 + (l & 31);
        a[f] = *(const bf16x8*)&As[cur][ra * 32 + (((ks * 2 + (l >> 5)) ^ (ra & 3)) << 3)];
        const int rb = wn + f * 32 + (l & 31);
        b[f] = *(const bf16x8*)&Bs[cur][rb * 32 + (((ks * 2 + (l >> 5)) ^ (rb & 3)) << 3)];
      }
#pragma unroll
      for (int i = 0; i < 2; ++i)
#pragma unroll
        for (int j = 0; j < 2; ++j)
          acc[i][j] = __builtin_amdgcn_mfma_f32_32x32x16_bf16(a[i], b[j], acc[i][j], 0, 0, 0);
    }
    __builtin_amdgcn_s_barrier();
  }

  const long msk = ((long)1 << p.rbs) - 1;
#pragma unroll
  for (int i = 0; i < 2; ++i)
#pragma unroll
    for (int j = 0; j < 2; ++j) {
      const int n = n0 + wn + j * 32 + (l & 31);
      if (n < p.N) {
#pragma unroll
        for (int reg = 0; reg < 16; ++reg) {
          const long row = m0 + wm + i * 32 + (reg & 3) + 8 * (reg >> 2) + 4 * (l >> 5);
          p.D[(row & msk) * p.s1 + (row >> p.rbs) * p.s2 + n] = acc[i][j][reg];
        }
      }
    }
}

// =============== batched enc_dot (split-bf16 MFMA): ed[b] = enc[b] @ wdec[:,b,:]^T ===============
__global__ __launch_bounds__(256) void encdot_kernel(const float* __restrict__ enc,
                                                     const u16* __restrict__ wh,
                                                     const u16* __restrict__ wl,
                                                     float* __restrict__ ed) {
  const int b = blockIdx.x;
  const int tid = threadIdx.x, l = tid & 63, w = tid >> 6;
  const int m0 = w * 32;
  const int lr = l & 15, lk = l >> 4;
  const float* eb = enc + (long)b * NTE * NH;
  f32x4 acc[2][2] = {};

#pragma unroll 1
  for (int ks = 0; ks < 16; ++ks) {
    const int k0 = ks * 32 + lk * 8;
    bf16x8 ah[2], alo[2];
#pragma unroll
    for (int mi = 0; mi < 2; ++mi) {
      const float* src = eb + (long)(m0 + mi * 16 + lr) * NH + k0;
      float4 x0 = *(const float4*)(src);
      float4 x1 = *(const float4*)(src + 4);
      float xs[8] = {x0.x, x0.y, x0.z, x0.w, x1.x, x1.y, x1.z, x1.w};
      bf16x8 h, lo;
#pragma unroll
      for (int q = 0; q < 8; ++q) {
        u16 hv = f2bf(xs[q]);
        h[q] = (short)hv;
        lo[q] = (short)f2bf(xs[q] - bf2f(hv));
      }
      ah[mi] = h; alo[mi] = lo;
    }
#pragma unroll
    for (int ni = 0; ni < 2; ++ni) {
      const long brow = ((long)(ni * 16 + lr) * NB + b) * 512 + k0;
      bf16x8 bh = *(const bf16x8*)(wh + brow);
      bf16x8 bl = *(const bf16x8*)(wl + brow);
#pragma unroll
      for (int mi = 0; mi < 2; ++mi) {
        acc[mi][ni] = __builtin_amdgcn_mfma_f32_16x16x32_bf16(ah[mi], bh, acc[mi][ni], 0, 0, 0);
        acc[mi][ni] = __builtin_amdgcn_mfma_f32_16x16x32_bf16(ah[mi], bl, acc[mi][ni], 0, 0, 0);
        acc[mi][ni] = __builtin_amdgcn_mfma_f32_16x16x32_bf16(alo[mi], bh, acc[mi][ni], 0, 0, 0);
      }
    }
  }

  const int cr = lk << 2;
  float* edb = ed + (long)b * NTE * ND;
#pragma unroll
  for (int mi = 0; mi < 2; ++mi)
#pragma unroll
    for (int ni = 0; ni < 2; ++ni)
#pragma unroll
      for (int j = 0; j < 4; ++j)
        edb[(long)(m0 + mi * 16 + cr + j) * ND + ni * 16 + lr] = acc[mi][ni][j];
}

// =============== per-step LSTM: grid (4 bg, 32 jg), block 256 = 4 waves ===============
__global__ __launch_bounds__(256) void step_lstm2(const u16* __restrict__ hprev, long ldh,
                                                  const u16* __restrict__ whh,
                                                  const u16* __restrict__ Gt,
                                                  float* __restrict__ c,
                                                  u16* __restrict__ hout) {
  __shared__ __align__(16) u16 WhhS[64 * 512];  // 64KB
  const int tid = threadIdx.x, l = tid & 63, w = tid >> 6;
  const int mb = blockIdx.x * 64, j0 = blockIdx.y * 16;

#pragma unroll
  for (int it = 0; it < 16; ++it) {
    const int row = it * 4 + w;
    const int g = row >> 4, r = row & 15;
    const long goff = ((long)(g * 512 + j0 + r)) * 512 + ((l ^ (row & 7)) << 3);
    g2l16(whh + goff, &WhhS[row * 512]);
  }

  bf16x8 av[16];
  const u16* hb = hprev + (long)(mb + w * 16 + (l & 15)) * ldh + ((l >> 4) << 3);
#pragma unroll
  for (int ks = 0; ks < 16; ++ks) av[ks] = *(const bf16x8*)(hb + ks * 32);

  __syncthreads();

  f32x4 acc[4] = {};
#pragma unroll
  for (int ks = 0; ks < 16; ++ks) {
#pragma unroll
    for (int g = 0; g < 4; ++g) {
      const int row = g * 16 + (l & 15);
      const int cl = (ks * 4 + (l >> 4)) ^ (l & 7);
      bf16x8 bv = *(const bf16x8*)((const char*)WhhS + row * 1024 + (cl << 4));
      acc[g] = __builtin_amdgcn_mfma_f32_16x16x32_bf16(av[ks], bv, acc[g], 0, 0, 0);
    }
  }

  const int j = j0 + (l & 15);
  const int bb = mb + w * 16 + ((l >> 4) << 2);
#pragma unroll
  for (int jr = 0; jr < 4; ++jr) {
    const int b = bb + jr;
    ushort4 gv = *(const ushort4*)(Gt + (long)b * 2048 + j * 4);  // {i,f,g,o} bf16
    float ig = sigm(acc[0][jr] + bf2f(gv.x));
    float fg = sigm(acc[1][jr] + bf2f(gv.y));
    float gg = tanhf(acc[2][jr] + bf2f(gv.z));
    float og = sigm(acc[3][jr] + bf2f(gv.w));
    const long ci = (long)b * NH + j;
    float cn = fg * c[ci] + ig * gg;
    c[ci] = cn;
    hout[(long)b * 1024 + j] = f2bf(og * tanhf(cn));
  }
}

// =============== v_norm rows -> bf16 [5120][320] (zero-padded) ===============
__global__ void vnorm_kernel(const float* __restrict__ v, u16* __restrict__ vn) {
  int r = blockIdx.x, tid = threadIdx.x;
  if (r >= NV) {
    for (int e = tid; e < 320; e += 64) vn[(long)r * 320 + e] = 0;
    return;
  }
  float ss = 0.f;
  for (int e = tid; e < NEMB; e += 64) { float x = v[(long)r * NEMB + e]; ss += x * x; }
#pragma unroll
  for (int o = 32; o > 0; o >>= 1) ss += __shfl_down(ss, o, 64);
  ss = __shfl(ss, 0, 64);
  float sc = 1.f / fmaxf(sqrtf(ss), 1e-12f);
  for (int e = tid; e < 320; e += 64)
    vn[(long)r * 320 + e] = (e < NEMB) ? f2bf(v[(long)r * NEMB + e] * sc) : (u16)0;
}

// =============== fused prep ===============
#define SEG_A 2621440L   // in_bf [8192][320]
#define SEG_B 81920L     // ws1_bf [256][320]
#define SEG_C 1703936L   // wih_bf [2048][832] gate-interleaved rows
#define SEG_D 1048576L   // whh_bf [2048][512]
#define SEG_E 393216L    // wv_bf [384][1024]
#define SEG_F 163840L    // wae hi/lo [512][320]
#define SEG_G 2048L      // bsumv gate-interleaved
#define SEG_H 131072L    // h0_bf
#define SEG_I 131072L    // c_buf = c0 copy
#define PREP_TOT (SEG_A + SEG_B + SEG_C + SEG_D + SEG_E + SEG_F + SEG_G + SEG_H + SEG_I)

__global__ void prep_all(const float* __restrict__ input, const float* __restrict__ Ws1,
                         const float* __restrict__ Wih, const float* __restrict__ Whh,
                         const float* __restrict__ Wv, const float* __restrict__ Watt,
                         const float* __restrict__ bih, const float* __restrict__ bhh,
                         const float* __restrict__ h0, const float* __restrict__ c0,
                         u16* __restrict__ in_bf, u16* __restrict__ ws1_bf,
                         u16* __restrict__ wih_bf, u16* __restrict__ whh_bf,
                         u16* __restrict__ wv_bf, u16* __restrict__ wae_hi,
                         u16* __restrict__ wae_lo,
                         float* __restrict__ bsumv, u16* __restrict__ h0_bf,
                         float* __restrict__ c_buf) {
  long idx = (long)blockIdx.x * 256 + threadIdx.x;
  if (idx < SEG_A) {
    int row = (int)(idx / 320), e = (int)(idx % 320);
    in_bf[idx] = (e < NEMB) ? f2bf(input[(long)row * NEMB + e]) : (u16)0;
    return;
  }
  idx -= SEG_A;
  if (idx < SEG_B) {
    int r = (int)(idx / 320), e = (int)(idx % 320);
    ws1_bf[idx] = (r < 150 && e < NEMB) ? f2bf(Ws1[r * NEMB + e]) : (u16)0;
    return;
  }
  idx -= SEG_B;
  if (idx < SEG_C) {
    int rp = (int)(idx / 832), cpos = (int)(idx % 832);
    int g = rp & 3, j = rp >> 2;
    wih_bf[idx] = (cpos < 812) ? f2bf(Wih[(long)(g * 512 + j) * 812 + cpos]) : (u16)0;
    return;
  }
  idx -= SEG_C;
  if (idx < SEG_D) { whh_bf[idx] = f2bf(Whh[idx]); return; }
  idx -= SEG_D;
  if (idx < SEG_E) {
    int r = (int)(idx >> 10);
    wv_bf[idx] = (r < NEMB) ? f2bf(Wv[idx]) : (u16)0;
    return;
  }
  idx -= SEG_E;
  if (idx < SEG_F) {  // wae hi/lo split
    int k = (int)(idx / 320), e = (int)(idx % 320);
    float x = (e < NEMB) ? Watt[(long)e * 1024 + 512 + k] : 0.f;
    u16 hv = f2bf(x);
    wae_hi[idx] = hv;
    wae_lo[idx] = f2bf(x - bf2f(hv));
    return;
  }
  idx -= SEG_F;
  if (idx < SEG_G) {
    int g = (int)(idx & 3), j = (int)(idx >> 2);
    bsumv[idx] = bih[g * 512 + j] + bhh[g * 512 + j];
    return;
  }
  idx -= SEG_G;
  if (idx < SEG_H) { h0_bf[idx] = f2bf(h0[idx]); return; }
  idx -= SEG_H;
  if (idx < SEG_I) c_buf[idx] = c0[idx];
}

// s_self[row] = Ws2b + sum_i tanh(hid[row][i]) * Ws2[i]
__global__ __launch_bounds__(256) void sself_reduce(const float* __restrict__ hid,
                                                    const float* __restrict__ Ws2,
                                                    const float* __restrict__ Ws2b,
                                                    float* __restrict__ s_self) {
  int row = blockIdx.x * 4 + (threadIdx.x >> 6);
  int lane = threadIdx.x & 63;
  float acc = 0.f;
  for (int i = lane; i < 150; i += 64) acc += tanhf(hid[(long)row * 160 + i]) * Ws2[i];
#pragma unroll
  for (int o = 32; o > 0; o >>= 1) acc += __shfl_down(acc, o, 64);
  if (lane == 0) s_self[row] = acc + Ws2b[0];
}

// =============== dec_inp: prefix-scan softmax -> dec hi/lo (split) + xcat ===============
__global__ __launch_bounds__(256) void decinp2_kernel(const float* __restrict__ input,
                                                      const float* __restrict__ s_self,
                                                      u16* __restrict__ dec_hi,
                                                      u16* __restrict__ dec_lo,
                                                      u16* __restrict__ xcat) {
  __shared__ float x[ND * NEMB];  // 38.4 KB
  __shared__ float ew[ND], invD[ND];
  const int b = blockIdx.x, tid = threadIdx.x;
  const float4* src = (const float4*)(input + (long)b * ND * NEMB);
  for (int i = tid; i < ND * NEMB / 4; i += 256) ((float4*)x)[i] = src[i];
  if (tid == 0) {
    float M = -1e30f;
    for (int u = 0; u < ND; u++) M = fmaxf(M, s_self[b * ND + u]);
    float s = 0.f;
    for (int u = 0; u < ND; u++) {
      float e = expf(s_self[b * ND + u] - M);
      ew[u] = e; s += e; invD[u] = 1.f / s;
    }
  }
  __syncthreads();
  for (int e = tid; e < NEMB; e += 256) {
    float acc = 0.f;
    for (int u = 0; u < ND; u++) {
      acc = fmaf(ew[u], x[u * NEMB + e], acc);
      float d = acc * invD[u];
      const long row = (long)u * NB + b;
      u16 hv = f2bf(d);
      dec_hi[row * 320 + e] = hv;
      dec_lo[row * 320 + e] = f2bf(d - bf2f(hv));
      xcat[row * 832 + e] = hv;
    }
  }
  for (int idx = tid; idx < ND * 20; idx += 256) {
    int u = idx / 20, e = 300 + idx % 20;
    const long row = (long)u * NB + b;
    dec_hi[row * 320 + e] = 0;
    dec_lo[row * 320 + e] = 0;
    xcat[row * 832 + 512 + e] = 0;  // K-pad cols 812..831
  }
}

// =============== enc-softmax + x_att -> bf16 into xcat[300..811] & hcat[512..1023] ===============
__global__ __launch_bounds__(256) void xatt_kernel(const float* __restrict__ enc_dot,
                                                   const float* __restrict__ enc,
                                                   u16* __restrict__ xcat,
                                                   u16* __restrict__ hcat) {
  __shared__ float al[NTE][ND + 1];
  int b = blockIdx.x, tid = threadIdx.x;
  for (int i = tid; i < NTE * ND; i += 256) al[i >> 5][i & 31] = enc_dot[(long)b * NTE * ND + i];
  __syncthreads();
  if (tid < ND) {
    int t = tid;
    float m = -1e30f;
    for (int tp = 0; tp < NTE; tp++) m = fmaxf(m, al[tp][t]);
    float s = 0.f;
    for (int tp = 0; tp < NTE; tp++) { float e = expf(al[tp][t] - m); al[tp][t] = e; s += e; }
    float inv = 1.f / s;
    for (int tp = 0; tp < NTE; tp++) al[tp][t] *= inv;
  }
  __syncthreads();
  int tx = tid & 31, ty = tid >> 5;
  const float* eb = enc + (long)b * NTE * NH;
  for (int hc = 0; hc < NH; hc += 128) {
    float acc[4][4] = {};
    for (int tp = 0; tp < NTE; tp++) {
      float4 ev = *(const float4*)(eb + (long)tp * NH + hc + (tx << 2));
#pragma unroll
      for (int i = 0; i < 4; i++) {
        float a = al[tp][(ty << 2) + i];
        acc[i][0] = fmaf(a, ev.x, acc[i][0]);
        acc[i][1] = fmaf(a, ev.y, acc[i][1]);
        acc[i][2] = fmaf(a, ev.z, acc[i][2]);
        acc[i][3] = fmaf(a, ev.w, acc[i][3]);
      }
    }
#pragma unroll
    for (int i = 0; i < 4; i++) {
      const long row = (long)((ty << 2) + i) * NB + b;
      const int h = hc + (tx << 2);
      ushort4 u;
      u.x = f2bf(acc[i][0]); u.y = f2bf(acc[i][1]);
      u.z = f2bf(acc[i][2]); u.w = f2bf(acc[i][3]);
      *(ushort4*)(xcat + row * 832 + 300 + h) = u;
      *(ushort4*)(hcat + row * 1024 + 512 + h) = u;
    }
  }
}

// =============== host ===============
extern "C" void kernel_launch(void* const* d_in, const int* in_sizes, int n_in,
                              void* d_out, int out_size, void* d_ws, size_t ws_size,
                              hipStream_t stream) {
  const float* input = (const float*)d_in[0];
  const float* enc   = (const float*)d_in[1];
  const float* h0   = (const float*)d_in[3];
  const float* c0   = (const float*)d_in[4];
  const float* Watt = (const float*)d_in[5];
  const float* Wv   = (const float*)d_in[7];
  const float* Wvb  = (const float*)d_in[8];
  const float* Ws1  = (const float*)d_in[9];
  const float* Ws1b = (const float*)d_in[10];
  const float* Ws2  = (const float*)d_in[11];
  const float* Ws2b = (const float*)d_in[12];
  const float* vmat = (const float*)d_in[13];
  const float* Wih  = (const float*)d_in[14];
  const float* Whh  = (const float*)d_in[15];
  const float* bih  = (const float*)d_in[16];
  const float* bhh  = (const float*)d_in[17];
  float* out = (float*)d_out;

  // workspace (float units, 16-float aligned)
  float* base = (float*)d_ws;
  size_t off = 0;
  auto alloc = [&](size_t n) { float* p = base + off; off += (n + 15) & ~15ull; return p; };
  u16* vnorm_bf = (u16*)alloc((size_t)5120 * 320 / 2);
  u16* wae_hi   = (u16*)alloc((size_t)512 * 320 / 2);
  u16* wae_lo   = (u16*)alloc((size_t)512 * 320 / 2);
  u16* wih_bf   = (u16*)alloc((size_t)2048 * 832 / 2);
  u16* whh_bf   = (u16*)alloc((size_t)2048 * 512 / 2);
  u16* wv_bf    = (u16*)alloc((size_t)384 * 1024 / 2);
  u16* ws1_bf   = (u16*)alloc((size_t)256 * 320 / 2);
  float* bsumv  = alloc(4 * NH);
  float* s_self = alloc(NB * ND);
  u16* dec_hi   = (u16*)alloc((size_t)ND * NB * 320 / 2);
  u16* dec_lo   = (u16*)alloc((size_t)ND * NB * 320 / 2);
  u16* xcat     = (u16*)alloc((size_t)ND * NB * 832 / 2);
  u16* hcat     = (u16*)alloc((size_t)ND * NB * 1024 / 2);
  u16* hi2_bf   = (u16*)alloc((size_t)ND * NB * 320 / 2);
  u16* h0_bf    = (u16*)alloc((size_t)NB * NH / 2);
  float* c_buf  = alloc((size_t)NB * NH);
  float* region = alloc((size_t)ND * NB * 4 * NH);  // 16.78M floats, overlaid:
  u16* wdec_hi  = (u16*)region;                      // [8192][512] u16 (floats 0..2.10M)
  u16* wdec_lo  = (u16*)(region + 2097152);          // [8192][512] u16 (2.10M..4.19M)
  float* enc_dot = region + 4194304;                 // [b][128][32] f32 (4.19M..5.24M)
  u16*   in_bf   = (u16*)(region + 6000000);         // [8192][320] bf16, dead after hid gemm
  float* hid     = region + 7500000;                 // [8192][160] f32, dead after sself_reduce
  u16*   inp_g   = (u16*)region;                     // [8192][2048] bf16, written after all die

  auto mg = [&](MGP p, int gm, int gn) { mg_gemm<<<dim3(gm, gn), 256, 0, stream>>>(p); };

  prep_all<<<(int)((PREP_TOT + 255) / 256), 256, 0, stream>>>(
      input, Ws1, Wih, Whh, Wv, Watt, bih, bhh, h0, c0,
      in_bf, ws1_bf, wih_bf, whh_bf, wv_bf, wae_hi, wae_lo, bsumv, h0_bf, c_buf);
  vnorm_kernel<<<5120, 64, 0, stream>>>(vmat, vnorm_bf);

  {  // hid = input-tanh GEMM: [8192][320] @ [256][320]^T -> fp32 [8192][160-strided], +Ws1b
    MGP p{};
    p.A = in_bf; p.lda = 320; p.B = ws1_bf; p.ldb = 320;
    p.D = hid; p.rbs = 30; p.s1 = 160; p.s2 = 0;
    p.bias = Ws1b; p.N = 150; p.K = 320;
    mg(p, 64, 2);
  }
  sself_reduce<<<2048, 256, 0, stream>>>(hid, Ws2, Ws2b, s_self);
  decinp2_kernel<<<NB, 256, 0, stream>>>(input, s_self, dec_hi, dec_lo, xcat);

  {  // wdec (split-bf16, 3 pairs, one dispatch): emits wdec hi/lo [8192][512]
    MGP p{};
    p.A = dec_hi; p.lda = 320; p.B = wae_hi; p.ldb = 320;
    p.A2 = dec_hi; p.B2 = wae_lo;
    p.A3 = dec_lo; p.B3 = wae_hi;
    p.rbs = 30;
    p.Dbf = wdec_hi; p.Dbf2 = wdec_lo; p.ldbf = 512; p.padN = 512;
    p.N = 512; p.K = 320;
    mg(p, 64, 4);
  }
  // enc_dot[b] = enc[b] @ wdec[:,b,:]^T (split-bf16 MFMA, in-register enc conversion)
  encdot_kernel<<<NB, 256, 0, stream>>>(enc, wdec_hi, wdec_lo, enc_dot);
  xatt_kernel<<<NB, 256, 0, stream>>>(enc_dot, enc, xcat, hcat);

  {  // inp_gates (gate-interleaved cols, bf16 out) = xcat @ WihP^T + biasP   [8192][2048]
    MGP p{};
    p.A = xcat; p.lda = 832; p.B = wih_bf; p.ldb = 832;
    p.rbs = 30;
    p.Dbf = inp_g; p.ldbf = 2048; p.padN = 2048;
    p.bias = bsumv; p.N = 2048; p.K = 832;
    mg(p, 64, 16);
  }

  // recurrence: one launch per step, 128 blocks (batch x j partition, no cross-block deps)
  for (int t = 0; t < ND; t++) {
    const u16* hp = (t == 0) ? h0_bf : (hcat + (size_t)(t - 1) * NB * 1024);
    long ldh = (t == 0) ? NH : 1024;
    step_lstm2<<<dim3(4, 32), 256, 0, stream>>>(hp, ldh, whh_bf,
                                                inp_g + (size_t)t * NB * 2048, c_buf,
                                                hcat + (size_t)t * NB * 1024);
  }

  {  // hi2 = [h|x_att] @ Wv^T + Wvb -> bf16 [8192][320]
    MGP p{};
    p.A = hcat; p.lda = 1024; p.B = wv_bf; p.ldb = 1024;
    p.rbs = 30;
    p.Dbf = hi2_bf; p.ldbf = 320; p.padN = 320;
    p.bias = Wvb; p.N = 300; p.K = 1024;
    mg(p, 64, 3);
  }
  {  // logits (32x32 MFMA, full-line fp32 stores): out[b][t][v] = hi2 . v_norm
    MG32 p{};
    p.A = hi2_bf; p.B = vnorm_bf;
    p.D = out; p.rbs = 8; p.s1 = (long)ND * NV; p.s2 = NV;
    p.N = NV; p.K = 320;
    mg_gemm32<<<dim3(64, 40), 256, 0, stream>>>(p);
  }
}